// Round 3
// baseline (185.948 us; speedup 1.0000x reference)
//
#include <hip/hip_runtime.h>
#include <math.h>

#define B_DIM 4
#define F_DIM 512
#define T_DIM 2048
#define H_DIM 4
#define HF    128

typedef __attribute__((ext_vector_type(8))) short short8;
typedef __attribute__((ext_vector_type(4))) float floatx4;

// round-half-up bf16 (2 inst)
__device__ __forceinline__ unsigned short f2bf(float f) {
    return (unsigned short)((__float_as_uint(f) + 0x8000u) >> 16);
}

// two floats -> packed bf16 pair: 2 adds + 1 v_perm_b32
__device__ __forceinline__ unsigned pkbf2(float a, float b) {
    const unsigned ua = __float_as_uint(a) + 0x8000u;
    const unsigned ub = __float_as_uint(b) + 0x8000u;
    return __builtin_amdgcn_perm(ub, ua, 0x07060302u);  // [ua.hi16 | ub.hi16]
}

__device__ __forceinline__ short8 pack8(const float* v) {
    union { unsigned u[4]; short8 s; } r;
    #pragma unroll
    for (int j = 0; j < 4; ++j) r.u[j] = pkbf2(v[2*j], v[2*j+1]);
    return r.s;
}

// direct-to-LDS 16B load: per-lane global src, wave-uniform LDS base + lane*16
__device__ __forceinline__ void gload16(const unsigned short* g, unsigned short* l) {
    __builtin_amdgcn_global_load_lds(
        (const __attribute__((address_space(1))) void*)g,
        (__attribute__((address_space(3))) void*)l, 16, 0, 0);
}

// ---------------- Kernel 0: prep ----------------
__global__ __launch_bounds__(256)
void prep_kernel(const float* __restrict__ x,
                 const float* __restrict__ Wq, const float* __restrict__ Wk,
                 const float* __restrict__ Wv,
                 unsigned short* __restrict__ xt,
                 unsigned short* __restrict__ Wqb, unsigned short* __restrict__ Wkb,
                 unsigned short* __restrict__ Wvb)
{
    const int tid = threadIdx.x;
    if (blockIdx.z < B_DIM) {
        const int b  = blockIdx.z;
        const int t0 = blockIdx.x * 64;
        const int f0 = blockIdx.y * 64;
        __shared__ float Ls[64][67];
        const float* __restrict__ xb = x + (size_t)b * F_DIM * T_DIM;
        #pragma unroll
        for (int it = 0; it < 4; ++it) {
            const int fr = (tid >> 4) + 16 * it;
            const int tc = (tid & 15) << 2;
            const float4 v = *(const float4*)(xb + (size_t)(f0 + fr) * T_DIM + t0 + tc);
            Ls[fr][tc+0] = v.x; Ls[fr][tc+1] = v.y; Ls[fr][tc+2] = v.z; Ls[fr][tc+3] = v.w;
        }
        __syncthreads();
        const int f8 = tid & 7;
        const int tb = tid >> 3;
        #pragma unroll
        for (int it2 = 0; it2 < 2; ++it2) {
            const int t = tb + 32 * it2;
            float v[8];
            #pragma unroll
            for (int j = 0; j < 8; ++j) v[j] = Ls[8*f8 + j][t];
            *(short8*)(xt + ((size_t)b * T_DIM + t0 + t) * F_DIM + f0 + 8*f8) = pack8(v);
        }
    } else {
        const int blockId = blockIdx.y * 32 + blockIdx.x;
        const int g0 = blockId * 256 + tid;
        const int perW = F_DIM * F_DIM / 8;
        for (int chunk = g0; chunk < 3 * perW; chunk += 65536) {
            const int wsel = chunk / perW;
            const int rem  = chunk - wsel * perW;
            const float* __restrict__ Ws = (wsel == 0) ? Wq : (wsel == 1) ? Wk : Wv;
            unsigned short* __restrict__ Wd = (wsel == 0) ? Wqb : (wsel == 1) ? Wkb : Wvb;
            float v[8];
            *(float4*)&v[0] = *(const float4*)(Ws + (size_t)rem * 8);
            *(float4*)&v[4] = *(const float4*)(Ws + (size_t)rem * 8 + 4);
            *(short8*)(Wd + (size_t)rem * 8) = pack8(v);
        }
    }
}

// ---------------- Kernel 1: merged QKV projection, BK=128 ----------------
#define ASTR 136   // 17 16B-granules per row (odd) -> all b128 accesses conflict-free

__global__ __launch_bounds__(256, 3)
void proj_kernel(const unsigned short* __restrict__ xt,
                 const unsigned short* __restrict__ Wqb,
                 const unsigned short* __restrict__ Wkb,
                 const unsigned short* __restrict__ Wvb,
                 const float* __restrict__ bq, const float* __restrict__ bk,
                 const float* __restrict__ bv,
                 unsigned short* __restrict__ Qb, unsigned short* __restrict__ Kb,
                 unsigned short* __restrict__ Vtb)
{
    __shared__ unsigned short As[128][ASTR];
    __shared__ unsigned short Bs[64][ASTR];

    const int tid  = threadIdx.x;
    const int w    = tid >> 6;
    const int lane = tid & 63;
    const int ln15 = lane & 15;
    const int quad = lane >> 4;

    const bool is_v = (blockIdx.z >= 8);
    int t0, fo0, b;
    const unsigned short *Asrc, *Bsrc;
    if (!is_v) {
        t0  = blockIdx.x * 128;
        fo0 = blockIdx.y * 64;
        b   = blockIdx.z >> 1;
        Asrc = xt + (size_t)b * T_DIM * F_DIM + (size_t)t0 * F_DIM;
        Bsrc = ((blockIdx.z & 1) ? Wkb : Wqb) + (size_t)fo0 * F_DIM;
    } else {
        const int idx = blockIdx.y * 16 + blockIdx.x;   // 0..127
        fo0 = (idx >> 5) * 128;
        t0  = (idx & 31) * 64;
        b   = blockIdx.z - 8;
        Asrc = Wvb + (size_t)fo0 * F_DIM;
        Bsrc = xt + (size_t)b * T_DIM * F_DIM + (size_t)t0 * F_DIM;
    }

    floatx4 acc[2][4];
    #pragma unroll
    for (int mi = 0; mi < 2; ++mi)
        #pragma unroll
        for (int nt = 0; nt < 4; ++nt) acc[mi][nt] = (floatx4){0.f,0.f,0.f,0.f};

    for (int f0 = 0; f0 < F_DIM; f0 += 128) {
        __syncthreads();
        #pragma unroll
        for (int it = 0; it < 8; ++it) {          // A: 128 rows x 16 chunks
            const int idx = tid + it * 256;
            const int r = idx >> 4, c = (idx & 15) * 8;
            *(short8*)&As[r][c] = *(const short8*)(Asrc + (size_t)r * F_DIM + f0 + c);
        }
        #pragma unroll
        for (int it = 0; it < 4; ++it) {          // B: 64 rows x 16 chunks
            const int idx = tid + it * 256;
            const int r = idx >> 4, c = (idx & 15) * 8;
            *(short8*)&Bs[r][c] = *(const short8*)(Bsrc + (size_t)r * F_DIM + f0 + c);
        }
        __syncthreads();
        #pragma unroll
        for (int ks = 0; ks < 4; ++ks) {
            short8 a[2], bb[4];
            a[0] = *(const short8*)&As[w*32      + ln15][ks*32 + quad*8];
            a[1] = *(const short8*)&As[w*32 + 16 + ln15][ks*32 + quad*8];
            #pragma unroll
            for (int nt = 0; nt < 4; ++nt)
                bb[nt] = *(const short8*)&Bs[16*nt + ln15][ks*32 + quad*8];
            #pragma unroll
            for (int mi = 0; mi < 2; ++mi)
                #pragma unroll
                for (int nt = 0; nt < 4; ++nt)
                    acc[mi][nt] = __builtin_amdgcn_mfma_f32_16x16x32_bf16(
                        a[mi], bb[nt], acc[mi][nt], 0, 0, 0);
        }
    }

    if (!is_v) {
        const int which = blockIdx.z & 1;
        const float* bias = which ? bk : bq;
        unsigned short* __restrict__ Out =
            (which ? Kb : Qb) + (size_t)b * T_DIM * F_DIM;
        const float oscale = which ? 1.0f : 0.0625f * 1.4426950408889634f;
        float bn[4];
        #pragma unroll
        for (int nt = 0; nt < 4; ++nt) bn[nt] = bias[fo0 + 16*nt + ln15];
        const float pw[2] = {
            __uint_as_float((unsigned)(123 - ln15) << 23),   // 2^-(ln15+4)
            __uint_as_float((unsigned)(107 - ln15) << 23)    // 2^-(ln15+20)
        };
        #pragma unroll
        for (int mi = 0; mi < 2; ++mi) {
            #pragma unroll
            for (int r = 0; r < 4; ++r) {
                const int t = t0 + w*32 + 16*mi + quad*4 + r;
                unsigned short* rowp = Out + (size_t)t * F_DIM + fo0;
                #pragma unroll
                for (int pr = 0; pr < 2; ++pr) {
                    const int wi = 16*pr + ln15;
                    const float re = acc[mi][pr  ][r] + bn[pr];
                    const float im = acc[mi][pr+2][r] + bn[pr+2];
                    const float u = (float)t * pw[pr];
                    float sn, cs;
                    __sincosf(u, &sn, &cs);
                    rowp[wi]      = f2bf((re * sn - im * cs) * oscale);
                    rowp[wi + 32] = f2bf((re * cs + im * sn) * oscale);
                }
            }
        }
    } else {
        #pragma unroll
        for (int mi = 0; mi < 2; ++mi) {
            #pragma unroll
            for (int r = 0; r < 4; ++r) {
                const int fo = fo0 + w*32 + 16*mi + quad*4 + r;
                const float bvv = bv[fo];
                unsigned short* rowp = Vtb + ((size_t)b * F_DIM + fo) * T_DIM + t0;
                #pragma unroll
                for (int nt = 0; nt < 4; ++nt)
                    rowp[16*nt + ln15] = f2bf(acc[mi][nt][r] + bvv);
            }
        }
    }
}

// ---------------- Kernel 2: S^T MFMA flash attention, 4-wave blocks --------
// R9: revert R8's register-hungry intra-wave pipeline (it spilled: WRITE_SIZE
// 332 MB scratch). Instead break SIMD phase-lockstep with inter-block TLP:
// block = 256 threads (4 waves x 32 q), full k-range, no split-K. 2 independent
// blocks/CU -> the 2 waves/SIMD come from different blocks with independent
// barriers, so one block's PV-MFMA overlaps the other's exp2/pack VALU phase.
// Compute body identical to the verified R7 order (no extra live state).
// setprio(1) around the PV MFMA cluster (role diversity now exists).
// Cross-half LDS reduction gone: each wave owns its q rows end-to-end.
__global__ __launch_bounds__(256, 2)
void attn_kernel(const unsigned short* __restrict__ Qb,
                 const unsigned short* __restrict__ Kb,
                 const unsigned short* __restrict__ Vtb,
                 const float* __restrict__ x,
                 const float* __restrict__ s2g,
                 float* __restrict__ out)
{
    __shared__ unsigned short smem[2][16384];   // [buf][K 8192 | V 8192] = 64 KB

    const int tid  = threadIdx.x;
    const int qg   = tid >> 6;        // wave = q-group = staging slice
    const int lane = tid & 63;
    const int ln15 = lane & 15;
    const int quad = lane >> 4;

    // XCD-chunked swizzle: 256 blocks, chunk 32 -> each XCD owns 2 (b,h) pairs
    const int flat = blockIdx.x + 16 * (blockIdx.y + 4 * blockIdx.z);
    const int swz  = (flat & 7) * 32 + (flat >> 3);
    const int q0 = (swz & 15) * 128;
    const int h  = (swz >> 4) & 3;
    const int b  = swz >> 6;

    const unsigned short* __restrict__ Qg =
        Qb + ((size_t)b * T_DIM + q0 + qg * 32) * F_DIM + h * HF;
    const unsigned short* __restrict__ Kg =
        Kb + (size_t)b * T_DIM * F_DIM + h * HF;
    const unsigned short* __restrict__ Vg =
        Vtb + ((size_t)b * F_DIM + h * HF) * T_DIM;

    // Per-lane inverse-swizzled global source offsets (gload_lds linear dest):
    //   K: forward perm rp = (r&32)|((r&4)<<2)|((r&24)>>1)|(r&3), col c^(rd&15)
    //   V: row rd = feat, col c^(rd&7)
    int koff[4], voff[4];
    #pragma unroll
    for (int it = 0; it < 4; ++it) {
        const int m = qg * 4 + it;
        {
            const int rd = 4 * m + (lane >> 4);
            const int r  = (rd & 32) | ((rd & 12) << 1) | ((rd & 16) >> 2) | (rd & 3);
            const int c  = (lane & 15) ^ (rd & 15);
            koff[it] = r * F_DIM + c * 8;
        }
        {
            const int rd = 8 * m + (lane >> 3);
            const int c  = (lane & 7) ^ (rd & 7);
            voff[it] = rd * T_DIM + c * 8;
        }
    }

    auto stage = [&](int buf, int k) {
        unsigned short* Kd = &smem[buf][0]    + qg * 2048;
        unsigned short* Vd = &smem[buf][8192] + qg * 2048;
        const unsigned short* Kp = Kg + (size_t)k * F_DIM;
        const unsigned short* Vp = Vg + k;
        #pragma unroll
        for (int it = 0; it < 4; ++it) {
            gload16(Kp + koff[it], Kd + it * 512);
            gload16(Vp + voff[it], Vd + it * 512);
        }
    };

    // Q B-frags (resident): B[k=feat][n=q=ln15], two 16-q groups
    short8 qa[2][4];
    #pragma unroll
    for (int g = 0; g < 2; ++g)
        #pragma unroll
        for (int c = 0; c < 4; ++c)
            qa[g][c] = *(const short8*)(Qg + (size_t)(g * 16 + ln15) * F_DIM + quad * 8 + 32 * c);

    floatx4 O1t[2][8], O2t[2][8];
    #pragma unroll
    for (int g = 0; g < 2; ++g)
        #pragma unroll
        for (int ft = 0; ft < 8; ++ft) {
            O1t[g][ft] = (floatx4){0.f, 0.f, 0.f, 0.f};
            O2t[g][ft] = (floatx4){0.f, 0.f, 0.f, 0.f};
        }
    float l1[2] = {0.f, 0.f}, l2[2] = {0.f, 0.f};

    stage(0, 0);   // prologue: tile 0 -> buf 0

    for (int k0o = 0; k0o < 2048; k0o += 128) {
        #pragma unroll
        for (int sub = 0; sub < 2; ++sub) {       // buf == sub (compile-time)
            const int k0 = k0o + sub * 64;
            asm volatile("s_waitcnt vmcnt(0)" ::: "memory");  // own tile DMA done
            __syncthreads();                                   // everyone's tile in LDS
            if (k0 + 64 < 2048) stage(sub ^ 1, k0 + 64);       // in flight across compute

            const unsigned short* Ks = &smem[sub][0];
            const unsigned short* Vs = &smem[sub][8192];

            // ---- scores S^T[k][q] + no-max softmax numerators p = 2^S ----
            short8 p1f[2][2], p2f[2][2];
            #pragma unroll
            for (int tp = 0; tp < 2; ++tp) {
                float e1[2][8], e2[2][8];
                #pragma unroll
                for (int tt = 0; tt < 2; ++tt) {
                    const int t = tp * 2 + tt;
                    const unsigned short* krow = &Ks[(16 * t + ln15) * 128];
                    const short8 k0f = *(const short8*)(krow + ((quad     ) ^ ln15) * 8);
                    const short8 k1f = *(const short8*)(krow + ((quad +  4) ^ ln15) * 8);
                    const short8 k2f = *(const short8*)(krow + ((quad +  8) ^ ln15) * 8);
                    const short8 k3f = *(const short8*)(krow + ((quad + 12) ^ ln15) * 8);
                    #pragma unroll
                    for (int g = 0; g < 2; ++g) {
                        floatx4 z = (floatx4){0.f, 0.f, 0.f, 0.f};
                        floatx4 s = __builtin_amdgcn_mfma_f32_16x16x32_bf16(k0f, qa[g][0], z, 0, 0, 0);
                        s         = __builtin_amdgcn_mfma_f32_16x16x32_bf16(k1f, qa[g][1], s, 0, 0, 0);
                        floatx4 u = __builtin_amdgcn_mfma_f32_16x16x32_bf16(k2f, qa[g][2], z, 0, 0, 0);
                        u         = __builtin_amdgcn_mfma_f32_16x16x32_bf16(k3f, qa[g][3], u, 0, 0, 0);
                        #pragma unroll
                        for (int r = 0; r < 4; ++r) {
                            e1[g][tt*4 + r] = __builtin_amdgcn_exp2f(s[r]);
                            e2[g][tt*4 + r] = __builtin_amdgcn_exp2f(u[r]);
                        }
                    }
                }
                #pragma unroll
                for (int g = 0; g < 2; ++g) {
                    #pragma unroll
                    for (int j = 0; j < 8; ++j) { l1[g] += e1[g][j]; l2[g] += e2[g][j]; }
                    p1f[g][tp] = pack8(&e1[g][0]);
                    p2f[g][tp] = pack8(&e2[g][0]);
                }
            }

            // ---- PV: O^T += V^T . P^T (each va read feeds 4 MFMAs) ----
            __builtin_amdgcn_s_setprio(1);
            #pragma unroll
            for (int p = 0; p < 2; ++p) {
                #pragma unroll
                for (int ft = 0; ft < 8; ++ft) {
                    const short8 va = *(const short8*)
                        (&Vs[(16*ft + ln15) * 64 + (((4*p + quad) ^ (ln15 & 7))) * 8]);
                    O1t[0][ft] = __builtin_amdgcn_mfma_f32_16x16x32_bf16(va, p1f[0][p], O1t[0][ft], 0, 0, 0);
                    O1t[1][ft] = __builtin_amdgcn_mfma_f32_16x16x32_bf16(va, p1f[1][p], O1t[1][ft], 0, 0, 0);
                    O2t[0][ft] = __builtin_amdgcn_mfma_f32_16x16x32_bf16(va, p2f[0][p], O2t[0][ft], 0, 0, 0);
                    O2t[1][ft] = __builtin_amdgcn_mfma_f32_16x16x32_bf16(va, p2f[1][p], O2t[1][ft], 0, 0, 0);
                }
            }
            __builtin_amdgcn_s_setprio(0);
        }
    }

    // ---- l reduction: intra-wave across quads (each wave owns its q rows) --
    #pragma unroll
    for (int g = 0; g < 2; ++g) {
        l1[g] += __shfl_xor(l1[g], 16); l1[g] += __shfl_xor(l1[g], 32);
        l2[g] += __shfl_xor(l2[g], 16); l2[g] += __shfl_xor(l2[g], 32);
    }

    // ---- epilogue: out = x + O1/l1 - s2*O2/l2, layout [B][F][T] ----
    const float s2h = s2g[h];
    float i1[2], i2[2];
    #pragma unroll
    for (int g = 0; g < 2; ++g) { i1[g] = 1.f / l1[g]; i2[g] = s2h / l2[g]; }
    const size_t obase = (size_t)b * F_DIM * T_DIM;
    const int f0 = h * HF;
    #pragma unroll
    for (int g = 0; g < 2; ++g) {
        const int t = q0 + qg*32 + g*16 + ln15;
        #pragma unroll
        for (int ft = 0; ft < 8; ++ft) {
            #pragma unroll
            for (int r = 0; r < 4; ++r) {
                const int feat = 16*ft + 4*quad + r;
                const size_t idx = obase + (size_t)(f0 + feat) * T_DIM + t;
                out[idx] = x[idx] + O1t[g][ft][r] * i1[g] - O2t[g][ft][r] * i2[g];
            }
        }
    }
}

extern "C" void kernel_launch(void* const* d_in, const int* in_sizes, int n_in,
                              void* d_out, int out_size, void* d_ws, size_t ws_size,
                              hipStream_t stream)
{
    const float* x  = (const float*)d_in[0];
    const float* Wq = (const float*)d_in[1];
    const float* bq = (const float*)d_in[2];
    const float* Wk = (const float*)d_in[3];
    const float* bk = (const float*)d_in[4];
    const float* Wv = (const float*)d_in[5];
    const float* bv = (const float*)d_in[6];
    const float* s2 = (const float*)d_in[7];
    float* out = (float*)d_out;

    const size_t per = (size_t)B_DIM * T_DIM * F_DIM;
    const size_t wsz = (size_t)F_DIM * F_DIM;
    unsigned short* xt  = (unsigned short*)d_ws;
    unsigned short* Wqb = xt + per;
    unsigned short* Wkb = Wqb + wsz;
    unsigned short* Wvb = Wkb + wsz;
    unsigned short* Qb  = Wvb + wsz;
    unsigned short* Kb  = Qb + per;
    unsigned short* Vtb = Kb + per;

    hipLaunchKernelGGL(prep_kernel, dim3(32, 8, 5), dim3(256), 0, stream,
                       x, Wq, Wk, Wv, xt, Wqb, Wkb, Wvb);

    hipLaunchKernelGGL(proj_kernel, dim3(16, 8, 12), dim3(256), 0, stream,
                       xt, Wqb, Wkb, Wvb, bq, bk, bv, Qb, Kb, Vtb);

    hipLaunchKernelGGL(attn_kernel, dim3(16, 4, 4), dim3(256), 0, stream,
                       Qb, Kb, Vtb, x, s2, out);
}

// Round 4
// 178.501 us; speedup vs baseline: 1.0417x; 1.0417x over previous
//
#include <hip/hip_runtime.h>
#include <math.h>

#define B_DIM 4
#define F_DIM 512
#define T_DIM 2048
#define H_DIM 4
#define HF    128

typedef __attribute__((ext_vector_type(8))) short short8;
typedef __attribute__((ext_vector_type(4))) float floatx4;

// round-half-up bf16 (2 inst)
__device__ __forceinline__ unsigned short f2bf(float f) {
    return (unsigned short)((__float_as_uint(f) + 0x8000u) >> 16);
}

// two floats -> packed bf16 pair: 2 adds + 1 v_perm_b32
__device__ __forceinline__ unsigned pkbf2(float a, float b) {
    const unsigned ua = __float_as_uint(a) + 0x8000u;
    const unsigned ub = __float_as_uint(b) + 0x8000u;
    return __builtin_amdgcn_perm(ub, ua, 0x07060302u);  // [ua.hi16 | ub.hi16]
}

__device__ __forceinline__ short8 pack8(const float* v) {
    union { unsigned u[4]; short8 s; } r;
    #pragma unroll
    for (int j = 0; j < 4; ++j) r.u[j] = pkbf2(v[2*j], v[2*j+1]);
    return r.s;
}

// direct-to-LDS 16B load: per-lane global src, wave-uniform LDS base + lane*16
__device__ __forceinline__ void gload16(const unsigned short* g, unsigned short* l) {
    __builtin_amdgcn_global_load_lds(
        (const __attribute__((address_space(1))) void*)g,
        (__attribute__((address_space(3))) void*)l, 16, 0, 0);
}

// ---------------- Kernel 0: prep ----------------
__global__ __launch_bounds__(256)
void prep_kernel(const float* __restrict__ x,
                 const float* __restrict__ Wq, const float* __restrict__ Wk,
                 const float* __restrict__ Wv,
                 unsigned short* __restrict__ xt,
                 unsigned short* __restrict__ Wqb, unsigned short* __restrict__ Wkb,
                 unsigned short* __restrict__ Wvb)
{
    const int tid = threadIdx.x;
    if (blockIdx.z < B_DIM) {
        const int b  = blockIdx.z;
        const int t0 = blockIdx.x * 64;
        const int f0 = blockIdx.y * 64;
        __shared__ float Ls[64][67];
        const float* __restrict__ xb = x + (size_t)b * F_DIM * T_DIM;
        #pragma unroll
        for (int it = 0; it < 4; ++it) {
            const int fr = (tid >> 4) + 16 * it;
            const int tc = (tid & 15) << 2;
            const float4 v = *(const float4*)(xb + (size_t)(f0 + fr) * T_DIM + t0 + tc);
            Ls[fr][tc+0] = v.x; Ls[fr][tc+1] = v.y; Ls[fr][tc+2] = v.z; Ls[fr][tc+3] = v.w;
        }
        __syncthreads();
        const int f8 = tid & 7;
        const int tb = tid >> 3;
        #pragma unroll
        for (int it2 = 0; it2 < 2; ++it2) {
            const int t = tb + 32 * it2;
            float v[8];
            #pragma unroll
            for (int j = 0; j < 8; ++j) v[j] = Ls[8*f8 + j][t];
            *(short8*)(xt + ((size_t)b * T_DIM + t0 + t) * F_DIM + f0 + 8*f8) = pack8(v);
        }
    } else {
        const int blockId = blockIdx.y * 32 + blockIdx.x;
        const int g0 = blockId * 256 + tid;
        const int perW = F_DIM * F_DIM / 8;
        for (int chunk = g0; chunk < 3 * perW; chunk += 65536) {
            const int wsel = chunk / perW;
            const int rem  = chunk - wsel * perW;
            const float* __restrict__ Ws = (wsel == 0) ? Wq : (wsel == 1) ? Wk : Wv;
            unsigned short* __restrict__ Wd = (wsel == 0) ? Wqb : (wsel == 1) ? Wkb : Wvb;
            float v[8];
            *(float4*)&v[0] = *(const float4*)(Ws + (size_t)rem * 8);
            *(float4*)&v[4] = *(const float4*)(Ws + (size_t)rem * 8 + 4);
            *(short8*)(Wd + (size_t)rem * 8) = pack8(v);
        }
    }
}

// ---------------- Kernel 1: merged QKV projection, BK=128 ----------------
#define ASTR 136   // 17 16B-granules per row (odd) -> all b128 accesses conflict-free

__global__ __launch_bounds__(256, 3)
void proj_kernel(const unsigned short* __restrict__ xt,
                 const unsigned short* __restrict__ Wqb,
                 const unsigned short* __restrict__ Wkb,
                 const unsigned short* __restrict__ Wvb,
                 const float* __restrict__ bq, const float* __restrict__ bk,
                 const float* __restrict__ bv,
                 unsigned short* __restrict__ Qb, unsigned short* __restrict__ Kb,
                 unsigned short* __restrict__ Vtb)
{
    __shared__ unsigned short As[128][ASTR];
    __shared__ unsigned short Bs[64][ASTR];

    const int tid  = threadIdx.x;
    const int w    = tid >> 6;
    const int lane = tid & 63;
    const int ln15 = lane & 15;
    const int quad = lane >> 4;

    const bool is_v = (blockIdx.z >= 8);
    int t0, fo0, b;
    const unsigned short *Asrc, *Bsrc;
    if (!is_v) {
        t0  = blockIdx.x * 128;
        fo0 = blockIdx.y * 64;
        b   = blockIdx.z >> 1;
        Asrc = xt + (size_t)b * T_DIM * F_DIM + (size_t)t0 * F_DIM;
        Bsrc = ((blockIdx.z & 1) ? Wkb : Wqb) + (size_t)fo0 * F_DIM;
    } else {
        const int idx = blockIdx.y * 16 + blockIdx.x;   // 0..127
        fo0 = (idx >> 5) * 128;
        t0  = (idx & 31) * 64;
        b   = blockIdx.z - 8;
        Asrc = Wvb + (size_t)fo0 * F_DIM;
        Bsrc = xt + (size_t)b * T_DIM * F_DIM + (size_t)t0 * F_DIM;
    }

    floatx4 acc[2][4];
    #pragma unroll
    for (int mi = 0; mi < 2; ++mi)
        #pragma unroll
        for (int nt = 0; nt < 4; ++nt) acc[mi][nt] = (floatx4){0.f,0.f,0.f,0.f};

    for (int f0 = 0; f0 < F_DIM; f0 += 128) {
        __syncthreads();
        #pragma unroll
        for (int it = 0; it < 8; ++it) {          // A: 128 rows x 16 chunks
            const int idx = tid + it * 256;
            const int r = idx >> 4, c = (idx & 15) * 8;
            *(short8*)&As[r][c] = *(const short8*)(Asrc + (size_t)r * F_DIM + f0 + c);
        }
        #pragma unroll
        for (int it = 0; it < 4; ++it) {          // B: 64 rows x 16 chunks
            const int idx = tid + it * 256;
            const int r = idx >> 4, c = (idx & 15) * 8;
            *(short8*)&Bs[r][c] = *(const short8*)(Bsrc + (size_t)r * F_DIM + f0 + c);
        }
        __syncthreads();
        #pragma unroll
        for (int ks = 0; ks < 4; ++ks) {
            short8 a[2], bb[4];
            a[0] = *(const short8*)&As[w*32      + ln15][ks*32 + quad*8];
            a[1] = *(const short8*)&As[w*32 + 16 + ln15][ks*32 + quad*8];
            #pragma unroll
            for (int nt = 0; nt < 4; ++nt)
                bb[nt] = *(const short8*)&Bs[16*nt + ln15][ks*32 + quad*8];
            #pragma unroll
            for (int mi = 0; mi < 2; ++mi)
                #pragma unroll
                for (int nt = 0; nt < 4; ++nt)
                    acc[mi][nt] = __builtin_amdgcn_mfma_f32_16x16x32_bf16(
                        a[mi], bb[nt], acc[mi][nt], 0, 0, 0);
        }
    }

    if (!is_v) {
        const int which = blockIdx.z & 1;
        const float* bias = which ? bk : bq;
        unsigned short* __restrict__ Out =
            (which ? Kb : Qb) + (size_t)b * T_DIM * F_DIM;
        const float oscale = which ? 1.0f : 0.0625f * 1.4426950408889634f;
        float bn[4];
        #pragma unroll
        for (int nt = 0; nt < 4; ++nt) bn[nt] = bias[fo0 + 16*nt + ln15];
        const float pw[2] = {
            __uint_as_float((unsigned)(123 - ln15) << 23),   // 2^-(ln15+4)
            __uint_as_float((unsigned)(107 - ln15) << 23)    // 2^-(ln15+20)
        };
        #pragma unroll
        for (int mi = 0; mi < 2; ++mi) {
            #pragma unroll
            for (int r = 0; r < 4; ++r) {
                const int t = t0 + w*32 + 16*mi + quad*4 + r;
                unsigned short* rowp = Out + (size_t)t * F_DIM + fo0;
                #pragma unroll
                for (int pr = 0; pr < 2; ++pr) {
                    const int wi = 16*pr + ln15;
                    const float re = acc[mi][pr  ][r] + bn[pr];
                    const float im = acc[mi][pr+2][r] + bn[pr+2];
                    const float u = (float)t * pw[pr];
                    float sn, cs;
                    __sincosf(u, &sn, &cs);
                    rowp[wi]      = f2bf((re * sn - im * cs) * oscale);
                    rowp[wi + 32] = f2bf((re * cs + im * sn) * oscale);
                }
            }
        }
    } else {
        #pragma unroll
        for (int mi = 0; mi < 2; ++mi) {
            #pragma unroll
            for (int r = 0; r < 4; ++r) {
                const int fo = fo0 + w*32 + 16*mi + quad*4 + r;
                const float bvv = bv[fo];
                unsigned short* rowp = Vtb + ((size_t)b * F_DIM + fo) * T_DIM + t0;
                #pragma unroll
                for (int nt = 0; nt < 4; ++nt)
                    rowp[16*nt + ln15] = f2bf(acc[mi][nt][r] + bvv);
            }
        }
    }
}

// ---------------- Kernel 2: S^T MFMA flash attention, nq=32/wave -----------
// R10: proven R7 base (512-thread split-K block, runtime-buf dbuf loop,
// global_load_lds staging, XCD swizzle) with tp-major compute order:
//   for tp in {0,1}: QK(t-tiles 2tp,2tp+1) -> SM(tp) -> PV(p=tp)
// PV's p index equals tp (p=0 eats k 0..31 = t-tiles 0,1), so each packed
// p-frag set dies right after its PV: peak liveness DROPS vs R7 (which held
// all 4 p-sets through both SM phases) -> no spill risk, and the iteration
// gains a second MFMA cluster interleaved with a second VALU stretch.
// setprio(1) wraps the pure-MFMA PV clusters (m191). l-sums tree-reduced.
__global__ __launch_bounds__(512, 2)
void attn_kernel(const unsigned short* __restrict__ Qb,
                 const unsigned short* __restrict__ Kb,
                 const unsigned short* __restrict__ Vtb,
                 const float* __restrict__ x,
                 const float* __restrict__ s2g,
                 float* __restrict__ out)
{
    __shared__ unsigned short smem[2][2][16384];   // [half][buf][K 8192 | V 8192] = 128 KB

    const int tid  = threadIdx.x;
    const int w8   = tid >> 6;
    const int half = w8 >> 2;
    const int qg   = w8 & 3;          // q-group index == staging slice index
    const int lane = tid & 63;
    const int ln15 = lane & 15;
    const int quad = lane >> 4;

    // XCD-chunked swizzle: 256 blocks, chunk 32 -> each XCD owns 2 (b,h) pairs
    const int flat = blockIdx.x + 16 * (blockIdx.y + 4 * blockIdx.z);
    const int swz  = (flat & 7) * 32 + (flat >> 3);
    const int q0 = (swz & 15) * 128;
    const int h  = (swz >> 4) & 3;
    const int b  = swz >> 6;

    const int kbase = half << 10;   // 0 or 1024

    const unsigned short* __restrict__ Qg =
        Qb + ((size_t)b * T_DIM + q0 + qg * 32) * F_DIM + h * HF;
    const unsigned short* __restrict__ Kg =
        Kb + (size_t)b * T_DIM * F_DIM + h * HF;
    const unsigned short* __restrict__ Vg =
        Vtb + ((size_t)b * F_DIM + h * HF) * T_DIM;

    // Per-lane inverse-swizzled global source offsets (gload_lds linear dest):
    //   K: forward perm rp = (r&32)|((r&4)<<2)|((r&24)>>1)|(r&3), col c^(rd&15)
    //   V: row rd = feat, col c^(rd&7)
    int koff[4], voff[4];
    #pragma unroll
    for (int it = 0; it < 4; ++it) {
        const int m = qg * 4 + it;
        {
            const int rd = 4 * m + (lane >> 4);
            const int r  = (rd & 32) | ((rd & 12) << 1) | ((rd & 16) >> 2) | (rd & 3);
            const int c  = (lane & 15) ^ (rd & 15);
            koff[it] = r * F_DIM + c * 8;
        }
        {
            const int rd = 8 * m + (lane >> 3);
            const int c  = (lane & 7) ^ (rd & 7);
            voff[it] = rd * T_DIM + c * 8;
        }
    }

    auto stage = [&](int buf, int k) {
        unsigned short* Kd = &smem[half][buf][0]    + qg * 2048;
        unsigned short* Vd = &smem[half][buf][8192] + qg * 2048;
        const unsigned short* Kp = Kg + (size_t)(kbase + k) * F_DIM;
        const unsigned short* Vp = Vg + (kbase + k);
        #pragma unroll
        for (int it = 0; it < 4; ++it) {
            gload16(Kp + koff[it], Kd + it * 512);
            gload16(Vp + voff[it], Vd + it * 512);
        }
    };

    // Q B-frags (resident): B[k=feat][n=q=ln15], two 16-q groups
    short8 qa[2][4];
    #pragma unroll
    for (int g = 0; g < 2; ++g)
        #pragma unroll
        for (int c = 0; c < 4; ++c)
            qa[g][c] = *(const short8*)(Qg + (size_t)(g * 16 + ln15) * F_DIM + quad * 8 + 32 * c);

    floatx4 O1t[2][8], O2t[2][8];
    #pragma unroll
    for (int g = 0; g < 2; ++g)
        #pragma unroll
        for (int ft = 0; ft < 8; ++ft) {
            O1t[g][ft] = (floatx4){0.f, 0.f, 0.f, 0.f};
            O2t[g][ft] = (floatx4){0.f, 0.f, 0.f, 0.f};
        }
    float l1[2] = {0.f, 0.f}, l2[2] = {0.f, 0.f};

    stage(0, 0);   // prologue: tile 0 -> buf 0

    for (int k0 = 0; k0 < 1024; k0 += 64) {
        asm volatile("s_waitcnt vmcnt(0)" ::: "memory");  // own tile-k0 DMA done
        __syncthreads();                                   // everyone's tile in LDS
        const int buf = (k0 >> 6) & 1;
        if (k0 + 64 < 1024) stage(buf ^ 1, k0 + 64);       // in flight across compute

        const unsigned short* Ks = &smem[half][buf][0];
        const unsigned short* Vs = &smem[half][buf][8192];

        #pragma unroll
        for (int tp = 0; tp < 2; ++tp) {
            // ---- QK: S^T[k][q] for t-tiles 2tp, 2tp+1 + exp2 numerators ----
            float e1[2][8], e2[2][8];
            #pragma unroll
            for (int tt = 0; tt < 2; ++tt) {
                const int t = tp * 2 + tt;
                const unsigned short* krow = &Ks[(16 * t + ln15) * 128];
                const short8 k0f = *(const short8*)(krow + ((quad     ) ^ ln15) * 8);
                const short8 k1f = *(const short8*)(krow + ((quad +  4) ^ ln15) * 8);
                const short8 k2f = *(const short8*)(krow + ((quad +  8) ^ ln15) * 8);
                const short8 k3f = *(const short8*)(krow + ((quad + 12) ^ ln15) * 8);
                #pragma unroll
                for (int g = 0; g < 2; ++g) {
                    floatx4 z = (floatx4){0.f, 0.f, 0.f, 0.f};
                    floatx4 s = __builtin_amdgcn_mfma_f32_16x16x32_bf16(k0f, qa[g][0], z, 0, 0, 0);
                    s         = __builtin_amdgcn_mfma_f32_16x16x32_bf16(k1f, qa[g][1], s, 0, 0, 0);
                    floatx4 u = __builtin_amdgcn_mfma_f32_16x16x32_bf16(k2f, qa[g][2], z, 0, 0, 0);
                    u         = __builtin_amdgcn_mfma_f32_16x16x32_bf16(k3f, qa[g][3], u, 0, 0, 0);
                    #pragma unroll
                    for (int r = 0; r < 4; ++r) {
                        e1[g][tt*4 + r] = __builtin_amdgcn_exp2f(s[r]);
                        e2[g][tt*4 + r] = __builtin_amdgcn_exp2f(u[r]);
                    }
                }
            }

            // ---- SM(tp): tree l-sums + pack (p-frags die after PV below) ----
            short8 p1f[2], p2f[2];
            #pragma unroll
            for (int g = 0; g < 2; ++g) {
                const float a1 = (e1[g][0] + e1[g][1]) + (e1[g][2] + e1[g][3]);
                const float b1 = (e1[g][4] + e1[g][5]) + (e1[g][6] + e1[g][7]);
                const float a2 = (e2[g][0] + e2[g][1]) + (e2[g][2] + e2[g][3]);
                const float b2 = (e2[g][4] + e2[g][5]) + (e2[g][6] + e2[g][7]);
                l1[g] += a1 + b1;
                l2[g] += a2 + b2;
                p1f[g] = pack8(&e1[g][0]);
                p2f[g] = pack8(&e2[g][0]);
            }

            // ---- PV(p=tp): O^T += V^T . P^T (pure-MFMA cluster) ----
            __builtin_amdgcn_s_setprio(1);
            #pragma unroll
            for (int ft = 0; ft < 8; ++ft) {
                const short8 va = *(const short8*)
                    (&Vs[(16*ft + ln15) * 64 + (((4*tp + quad) ^ (ln15 & 7))) * 8]);
                O1t[0][ft] = __builtin_amdgcn_mfma_f32_16x16x32_bf16(va, p1f[0], O1t[0][ft], 0, 0, 0);
                O1t[1][ft] = __builtin_amdgcn_mfma_f32_16x16x32_bf16(va, p1f[1], O1t[1][ft], 0, 0, 0);
                O2t[0][ft] = __builtin_amdgcn_mfma_f32_16x16x32_bf16(va, p2f[0], O2t[0][ft], 0, 0, 0);
                O2t[1][ft] = __builtin_amdgcn_mfma_f32_16x16x32_bf16(va, p2f[1], O2t[1][ft], 0, 0, 0);
            }
            __builtin_amdgcn_s_setprio(0);
        }
    }

    // ---- reductions: intra-wave l across quads, then cross-half via LDS ----
    #pragma unroll
    for (int g = 0; g < 2; ++g) {
        l1[g] += __shfl_xor(l1[g], 16); l1[g] += __shfl_xor(l1[g], 32);
        l2[g] += __shfl_xor(l2[g], 16); l2[g] += __shfl_xor(l2[g], 32);
    }

    float* comb = (float*)&smem[0][0][0];
    __syncthreads();   // all compute done, smem reusable
    if (half == 1) {
        if (quad == 0) {
            #pragma unroll
            for (int g = 0; g < 2; ++g) {
                comb[      qg*32 + g*16 + ln15] = l1[g];
                comb[128 + qg*32 + g*16 + ln15] = l2[g];
            }
        }
        #pragma unroll
        for (int g = 0; g < 2; ++g)
            #pragma unroll
            for (int ft = 0; ft < 8; ++ft)
                #pragma unroll
                for (int r = 0; r < 4; ++r)
                    comb[512 + (((g*8 + ft)*4 + r) * 256) + qg*64 + lane] = O1t[g][ft][r];
    }
    __syncthreads();
    if (half == 0) {
        #pragma unroll
        for (int g = 0; g < 2; ++g) {
            l1[g] += comb[      qg*32 + g*16 + ln15];
            l2[g] += comb[128 + qg*32 + g*16 + ln15];
        }
        #pragma unroll
        for (int g = 0; g < 2; ++g)
            #pragma unroll
            for (int ft = 0; ft < 8; ++ft)
                #pragma unroll
                for (int r = 0; r < 4; ++r)
                    O1t[g][ft][r] += comb[512 + (((g*8 + ft)*4 + r) * 256) + qg*64 + lane];
    }
    __syncthreads();
    if (half == 1) {
        #pragma unroll
        for (int g = 0; g < 2; ++g)
            #pragma unroll
            for (int ft = 0; ft < 8; ++ft)
                #pragma unroll
                for (int r = 0; r < 4; ++r)
                    comb[512 + (((g*8 + ft)*4 + r) * 256) + qg*64 + lane] = O2t[g][ft][r];
    }
    __syncthreads();
    if (half == 0) {
        #pragma unroll
        for (int g = 0; g < 2; ++g)
            #pragma unroll
            for (int ft = 0; ft < 8; ++ft)
                #pragma unroll
                for (int r = 0; r < 4; ++r)
                    O2t[g][ft][r] += comb[512 + (((g*8 + ft)*4 + r) * 256) + qg*64 + lane];

        // ---- epilogue: out = x + O1/l1 - s2*O2/l2, layout [B][F][T] ----
        const float s2h = s2g[h];
        float i1[2], i2[2];
        #pragma unroll
        for (int g = 0; g < 2; ++g) { i1[g] = 1.f / l1[g]; i2[g] = s2h / l2[g]; }
        const size_t obase = (size_t)b * F_DIM * T_DIM;
        const int f0 = h * HF;
        #pragma unroll
        for (int g = 0; g < 2; ++g) {
            const int t = q0 + qg*32 + g*16 + ln15;
            #pragma unroll
            for (int ft = 0; ft < 8; ++ft) {
                #pragma unroll
                for (int r = 0; r < 4; ++r) {
                    const int feat = 16*ft + 4*quad + r;
                    const size_t idx = obase + (size_t)(f0 + feat) * T_DIM + t;
                    out[idx] = x[idx] + O1t[g][ft][r] * i1[g] - O2t[g][ft][r] * i2[g];
                }
            }
        }
    }
}

extern "C" void kernel_launch(void* const* d_in, const int* in_sizes, int n_in,
                              void* d_out, int out_size, void* d_ws, size_t ws_size,
                              hipStream_t stream)
{
    const float* x  = (const float*)d_in[0];
    const float* Wq = (const float*)d_in[1];
    const float* bq = (const float*)d_in[2];
    const float* Wk = (const float*)d_in[3];
    const float* bk = (const float*)d_in[4];
    const float* Wv = (const float*)d_in[5];
    const float* bv = (const float*)d_in[6];
    const float* s2 = (const float*)d_in[7];
    float* out = (float*)d_out;

    const size_t per = (size_t)B_DIM * T_DIM * F_DIM;
    const size_t wsz = (size_t)F_DIM * F_DIM;
    unsigned short* xt  = (unsigned short*)d_ws;
    unsigned short* Wqb = xt + per;
    unsigned short* Wkb = Wqb + wsz;
    unsigned short* Wvb = Wkb + wsz;
    unsigned short* Qb  = Wvb + wsz;
    unsigned short* Kb  = Qb + per;
    unsigned short* Vtb = Kb + per;

    hipLaunchKernelGGL(prep_kernel, dim3(32, 8, 5), dim3(256), 0, stream,
                       x, Wq, Wk, Wv, xt, Wqb, Wkb, Wvb);

    hipLaunchKernelGGL(proj_kernel, dim3(16, 8, 12), dim3(256), 0, stream,
                       xt, Wqb, Wkb, Wvb, bq, bk, bv, Qb, Kb, Vtb);

    hipLaunchKernelGGL(attn_kernel, dim3(16, 4, 4), dim3(512), 0, stream,
                       Qb, Kb, Vtb, x, s2, out);
}

// Round 5
// 111.035 us; speedup vs baseline: 1.6747x; 1.6076x over previous
//
#include <hip/hip_runtime.h>
#include <math.h>

#define B_DIM 4
#define F_DIM 512
#define T_DIM 2048
#define H_DIM 4
#define HF    128

typedef __attribute__((ext_vector_type(8))) short short8;
typedef __attribute__((ext_vector_type(4))) float floatx4;

// round-half-up bf16 (2 inst)
__device__ __forceinline__ unsigned short f2bf(float f) {
    return (unsigned short)((__float_as_uint(f) + 0x8000u) >> 16);
}

// two floats -> packed bf16 pair: 2 adds + 1 v_perm_b32
__device__ __forceinline__ unsigned pkbf2(float a, float b) {
    const unsigned ua = __float_as_uint(a) + 0x8000u;
    const unsigned ub = __float_as_uint(b) + 0x8000u;
    return __builtin_amdgcn_perm(ub, ua, 0x07060302u);  // [ua.hi16 | ub.hi16]
}

__device__ __forceinline__ short8 pack8(const float* v) {
    union { unsigned u[4]; short8 s; } r;
    #pragma unroll
    for (int j = 0; j < 4; ++j) r.u[j] = pkbf2(v[2*j], v[2*j+1]);
    return r.s;
}

// direct-to-LDS 16B load: per-lane global src, wave-uniform LDS base + lane*16
__device__ __forceinline__ void gload16(const unsigned short* g, unsigned short* l) {
    __builtin_amdgcn_global_load_lds(
        (const __attribute__((address_space(1))) void*)g,
        (__attribute__((address_space(3))) void*)l, 16, 0, 0);
}

// ---------------- Kernel 0: prep ----------------
__global__ __launch_bounds__(256)
void prep_kernel(const float* __restrict__ x,
                 const float* __restrict__ Wq, const float* __restrict__ Wk,
                 const float* __restrict__ Wv,
                 unsigned short* __restrict__ xt,
                 unsigned short* __restrict__ Wqb, unsigned short* __restrict__ Wkb,
                 unsigned short* __restrict__ Wvb)
{
    const int tid = threadIdx.x;
    if (blockIdx.z < B_DIM) {
        const int b  = blockIdx.z;
        const int t0 = blockIdx.x * 64;
        const int f0 = blockIdx.y * 64;
        __shared__ float Ls[64][67];
        const float* __restrict__ xb = x + (size_t)b * F_DIM * T_DIM;
        #pragma unroll
        for (int it = 0; it < 4; ++it) {
            const int fr = (tid >> 4) + 16 * it;
            const int tc = (tid & 15) << 2;
            const float4 v = *(const float4*)(xb + (size_t)(f0 + fr) * T_DIM + t0 + tc);
            Ls[fr][tc+0] = v.x; Ls[fr][tc+1] = v.y; Ls[fr][tc+2] = v.z; Ls[fr][tc+3] = v.w;
        }
        __syncthreads();
        const int f8 = tid & 7;
        const int tb = tid >> 3;
        #pragma unroll
        for (int it2 = 0; it2 < 2; ++it2) {
            const int t = tb + 32 * it2;
            float v[8];
            #pragma unroll
            for (int j = 0; j < 8; ++j) v[j] = Ls[8*f8 + j][t];
            *(short8*)(xt + ((size_t)b * T_DIM + t0 + t) * F_DIM + f0 + 8*f8) = pack8(v);
        }
    } else {
        const int blockId = blockIdx.y * 32 + blockIdx.x;
        const int g0 = blockId * 256 + tid;
        const int perW = F_DIM * F_DIM / 8;
        for (int chunk = g0; chunk < 3 * perW; chunk += 65536) {
            const int wsel = chunk / perW;
            const int rem  = chunk - wsel * perW;
            const float* __restrict__ Ws = (wsel == 0) ? Wq : (wsel == 1) ? Wk : Wv;
            unsigned short* __restrict__ Wd = (wsel == 0) ? Wqb : (wsel == 1) ? Wkb : Wvb;
            float v[8];
            *(float4*)&v[0] = *(const float4*)(Ws + (size_t)rem * 8);
            *(float4*)&v[4] = *(const float4*)(Ws + (size_t)rem * 8 + 4);
            *(short8*)(Wd + (size_t)rem * 8) = pack8(v);
        }
    }
}

// ---------------- Kernel 1: merged QKV projection, BK=128 ----------------
#define ASTR 136   // 17 16B-granules per row (odd) -> all b128 accesses conflict-free

__global__ __launch_bounds__(256, 3)
void proj_kernel(const unsigned short* __restrict__ xt,
                 const unsigned short* __restrict__ Wqb,
                 const unsigned short* __restrict__ Wkb,
                 const unsigned short* __restrict__ Wvb,
                 const float* __restrict__ bq, const float* __restrict__ bk,
                 const float* __restrict__ bv,
                 unsigned short* __restrict__ Qb, unsigned short* __restrict__ Kb,
                 unsigned short* __restrict__ Vtb)
{
    __shared__ unsigned short As[128][ASTR];
    __shared__ unsigned short Bs[64][ASTR];

    const int tid  = threadIdx.x;
    const int w    = tid >> 6;
    const int lane = tid & 63;
    const int ln15 = lane & 15;
    const int quad = lane >> 4;

    // R11: XCD-chunked swizzle of the 128-block (x,y) plane (z untouched):
    // each XCD keeps one 64-row W panel L2-resident. Perf heuristic only.
    const int flat = blockIdx.x + 16 * blockIdx.y;       // 0..127
    const int fswz = (flat & 7) * 16 + (flat >> 3);      // bijective, 128%8==0
    const int bx   = fswz & 15;
    const int by   = fswz >> 4;

    const bool is_v = (blockIdx.z >= 8);
    int t0, fo0, b;
    const unsigned short *Asrc, *Bsrc;
    if (!is_v) {
        t0  = bx * 128;
        fo0 = by * 64;
        b   = blockIdx.z >> 1;
        Asrc = xt + (size_t)b * T_DIM * F_DIM + (size_t)t0 * F_DIM;
        Bsrc = ((blockIdx.z & 1) ? Wkb : Wqb) + (size_t)fo0 * F_DIM;
    } else {
        const int idx = fswz;                            // 0..127
        fo0 = (idx >> 5) * 128;
        t0  = (idx & 31) * 64;
        b   = blockIdx.z - 8;
        Asrc = Wvb + (size_t)fo0 * F_DIM;
        Bsrc = xt + (size_t)b * T_DIM * F_DIM + (size_t)t0 * F_DIM;
    }

    floatx4 acc[2][4];
    #pragma unroll
    for (int mi = 0; mi < 2; ++mi)
        #pragma unroll
        for (int nt = 0; nt < 4; ++nt) acc[mi][nt] = (floatx4){0.f,0.f,0.f,0.f};

    for (int f0 = 0; f0 < F_DIM; f0 += 128) {
        __syncthreads();
        #pragma unroll
        for (int it = 0; it < 8; ++it) {          // A: 128 rows x 16 chunks
            const int idx = tid + it * 256;
            const int r = idx >> 4, c = (idx & 15) * 8;
            *(short8*)&As[r][c] = *(const short8*)(Asrc + (size_t)r * F_DIM + f0 + c);
        }
        #pragma unroll
        for (int it = 0; it < 4; ++it) {          // B: 64 rows x 16 chunks
            const int idx = tid + it * 256;
            const int r = idx >> 4, c = (idx & 15) * 8;
            *(short8*)&Bs[r][c] = *(const short8*)(Bsrc + (size_t)r * F_DIM + f0 + c);
        }
        __syncthreads();
        #pragma unroll
        for (int ks = 0; ks < 4; ++ks) {
            short8 a[2], bb[4];
            a[0] = *(const short8*)&As[w*32      + ln15][ks*32 + quad*8];
            a[1] = *(const short8*)&As[w*32 + 16 + ln15][ks*32 + quad*8];
            #pragma unroll
            for (int nt = 0; nt < 4; ++nt)
                bb[nt] = *(const short8*)&Bs[16*nt + ln15][ks*32 + quad*8];
            #pragma unroll
            for (int mi = 0; mi < 2; ++mi)
                #pragma unroll
                for (int nt = 0; nt < 4; ++nt)
                    acc[mi][nt] = __builtin_amdgcn_mfma_f32_16x16x32_bf16(
                        a[mi], bb[nt], acc[mi][nt], 0, 0, 0);
        }
    }

    if (!is_v) {
        const int which = blockIdx.z & 1;
        const float* bias = which ? bk : bq;
        unsigned short* __restrict__ Out =
            (which ? Kb : Qb) + (size_t)b * T_DIM * F_DIM;
        // Q carries 1/sqrt(F/2) * log2(e) so attn can use exp2 (v_exp_f32 native)
        const float oscale = which ? 1.0f : 0.0625f * 1.4426950408889634f;
        float bn[4];
        #pragma unroll
        for (int nt = 0; nt < 4; ++nt) bn[nt] = bias[fo0 + 16*nt + ln15];
        const float pw[2] = {
            __uint_as_float((unsigned)(123 - ln15) << 23),   // 2^-(ln15+4)
            __uint_as_float((unsigned)(107 - ln15) << 23)    // 2^-(ln15+20)
        };
        #pragma unroll
        for (int mi = 0; mi < 2; ++mi) {
            #pragma unroll
            for (int r = 0; r < 4; ++r) {
                const int t = t0 + w*32 + 16*mi + quad*4 + r;
                unsigned short* rowp = Out + (size_t)t * F_DIM + fo0;
                #pragma unroll
                for (int pr = 0; pr < 2; ++pr) {
                    const int wi = 16*pr + ln15;
                    const float re = acc[mi][pr  ][r] + bn[pr];
                    const float im = acc[mi][pr+2][r] + bn[pr+2];
                    const float u = (float)t * pw[pr];
                    float sn, cs;
                    __sincosf(u, &sn, &cs);
                    rowp[wi]      = f2bf((re * sn - im * cs) * oscale);
                    rowp[wi + 32] = f2bf((re * cs + im * sn) * oscale);
                }
            }
        }
    } else {
        #pragma unroll
        for (int mi = 0; mi < 2; ++mi) {
            #pragma unroll
            for (int r = 0; r < 4; ++r) {
                const int fo = fo0 + w*32 + 16*mi + quad*4 + r;
                const float bvv = bv[fo];
                unsigned short* rowp = Vtb + ((size_t)b * F_DIM + fo) * T_DIM + t0;
                #pragma unroll
                for (int nt = 0; nt < 4; ++nt)
                    rowp[16*nt + ln15] = f2bf(acc[mi][nt][r] + bvv);
            }
        }
    }
}

// ---------------- Kernel 2: S^T MFMA flash attention, nq=32/wave -----------
// R11: byte-exact restore of the proven R7 kernel (attn ~70 us, no spill;
// R8/R9/R10 reorders all spilled to scratch — this schedule is the one the
// allocator fits in 256 regs). Single liveness-neutral delta: tree-reduced
// l-sums (reorders adds among values already live for pack8; temporaries die
// immediately, nothing new crosses an MFMA cluster).
__global__ __launch_bounds__(512, 2)
void attn_kernel(const unsigned short* __restrict__ Qb,
                 const unsigned short* __restrict__ Kb,
                 const unsigned short* __restrict__ Vtb,
                 const float* __restrict__ x,
                 const float* __restrict__ s2g,
                 float* __restrict__ out)
{
    __shared__ unsigned short smem[2][2][16384];   // [half][buf][K 8192 | V 8192] = 128 KB

    const int tid  = threadIdx.x;
    const int w8   = tid >> 6;
    const int half = w8 >> 2;
    const int qg   = w8 & 3;          // q-group index == staging slice index
    const int lane = tid & 63;
    const int ln15 = lane & 15;
    const int quad = lane >> 4;

    // XCD-chunked swizzle: 256 blocks, chunk 32 -> each XCD owns 2 (b,h) pairs
    const int flat = blockIdx.x + 16 * (blockIdx.y + 4 * blockIdx.z);
    const int swz  = (flat & 7) * 32 + (flat >> 3);
    const int q0 = (swz & 15) * 128;
    const int h  = (swz >> 4) & 3;
    const int b  = swz >> 6;

    const int kbase = half << 10;   // 0 or 1024

    const unsigned short* __restrict__ Qg =
        Qb + ((size_t)b * T_DIM + q0 + qg * 32) * F_DIM + h * HF;
    const unsigned short* __restrict__ Kg =
        Kb + (size_t)b * T_DIM * F_DIM + h * HF;
    const unsigned short* __restrict__ Vg =
        Vtb + ((size_t)b * F_DIM + h * HF) * T_DIM;

    // Per-lane inverse-swizzled global source offsets (gload_lds linear dest):
    //   K: forward perm rp = (r&32)|((r&4)<<2)|((r&24)>>1)|(r&3), col c^(rd&15)
    //   V: row rd = feat, col c^(rd&7)
    int koff[4], voff[4];
    #pragma unroll
    for (int it = 0; it < 4; ++it) {
        const int m = qg * 4 + it;
        {
            const int rd = 4 * m + (lane >> 4);
            const int r  = (rd & 32) | ((rd & 12) << 1) | ((rd & 16) >> 2) | (rd & 3);
            const int c  = (lane & 15) ^ (rd & 15);
            koff[it] = r * F_DIM + c * 8;
        }
        {
            const int rd = 8 * m + (lane >> 3);
            const int c  = (lane & 7) ^ (rd & 7);
            voff[it] = rd * T_DIM + c * 8;
        }
    }

    auto stage = [&](int buf, int k) {
        unsigned short* Kd = &smem[half][buf][0]    + qg * 2048;
        unsigned short* Vd = &smem[half][buf][8192] + qg * 2048;
        const unsigned short* Kp = Kg + (size_t)(kbase + k) * F_DIM;
        const unsigned short* Vp = Vg + (kbase + k);
        #pragma unroll
        for (int it = 0; it < 4; ++it) {
            gload16(Kp + koff[it], Kd + it * 512);
            gload16(Vp + voff[it], Vd + it * 512);
        }
    };

    // Q B-frags (resident): B[k=feat][n=q=ln15], two 16-q groups
    short8 qa[2][4];
    #pragma unroll
    for (int g = 0; g < 2; ++g)
        #pragma unroll
        for (int c = 0; c < 4; ++c)
            qa[g][c] = *(const short8*)(Qg + (size_t)(g * 16 + ln15) * F_DIM + quad * 8 + 32 * c);

    floatx4 O1t[2][8], O2t[2][8];
    #pragma unroll
    for (int g = 0; g < 2; ++g)
        #pragma unroll
        for (int ft = 0; ft < 8; ++ft) {
            O1t[g][ft] = (floatx4){0.f, 0.f, 0.f, 0.f};
            O2t[g][ft] = (floatx4){0.f, 0.f, 0.f, 0.f};
        }
    float l1[2] = {0.f, 0.f}, l2[2] = {0.f, 0.f};

    stage(0, 0);   // prologue: tile 0 -> buf 0

    for (int k0 = 0; k0 < 1024; k0 += 64) {
        asm volatile("s_waitcnt vmcnt(0)" ::: "memory");  // own tile-k0 DMA done
        __syncthreads();                                   // everyone's tile in LDS
        const int buf = (k0 >> 6) & 1;
        if (k0 + 64 < 1024) stage(buf ^ 1, k0 + 64);       // in flight across compute

        const unsigned short* Ks = &smem[half][buf][0];
        const unsigned short* Vs = &smem[half][buf][8192];

        // ---- scores S^T[k][q] + no-max softmax numerators p = 2^S ----
        short8 p1f[2][2], p2f[2][2];
        #pragma unroll
        for (int tp = 0; tp < 2; ++tp) {
            float e1[2][8], e2[2][8];
            #pragma unroll
            for (int tt = 0; tt < 2; ++tt) {
                const int t = tp * 2 + tt;
                const unsigned short* krow = &Ks[(16 * t + ln15) * 128];
                const short8 k0f = *(const short8*)(krow + ((quad     ) ^ ln15) * 8);
                const short8 k1f = *(const short8*)(krow + ((quad +  4) ^ ln15) * 8);
                const short8 k2f = *(const short8*)(krow + ((quad +  8) ^ ln15) * 8);
                const short8 k3f = *(const short8*)(krow + ((quad + 12) ^ ln15) * 8);
                #pragma unroll
                for (int g = 0; g < 2; ++g) {
                    floatx4 z = (floatx4){0.f, 0.f, 0.f, 0.f};
                    floatx4 s = __builtin_amdgcn_mfma_f32_16x16x32_bf16(k0f, qa[g][0], z, 0, 0, 0);
                    s         = __builtin_amdgcn_mfma_f32_16x16x32_bf16(k1f, qa[g][1], s, 0, 0, 0);
                    floatx4 u = __builtin_amdgcn_mfma_f32_16x16x32_bf16(k2f, qa[g][2], z, 0, 0, 0);
                    u         = __builtin_amdgcn_mfma_f32_16x16x32_bf16(k3f, qa[g][3], u, 0, 0, 0);
                    #pragma unroll
                    for (int r = 0; r < 4; ++r) {
                        e1[g][tt*4 + r] = __builtin_amdgcn_exp2f(s[r]);
                        e2[g][tt*4 + r] = __builtin_amdgcn_exp2f(u[r]);
                    }
                }
            }
            #pragma unroll
            for (int g = 0; g < 2; ++g) {
                // tree-reduced l-sums (R11): depth 4 instead of 8, same values
                l1[g] += ((e1[g][0] + e1[g][1]) + (e1[g][2] + e1[g][3]))
                       + ((e1[g][4] + e1[g][5]) + (e1[g][6] + e1[g][7]));
                l2[g] += ((e2[g][0] + e2[g][1]) + (e2[g][2] + e2[g][3]))
                       + ((e2[g][4] + e2[g][5]) + (e2[g][6] + e2[g][7]));
                p1f[g][tp] = pack8(&e1[g][0]);
                p2f[g][tp] = pack8(&e2[g][0]);
            }
        }

        // ---- PV: O^T += V^T . P^T (each va read feeds 4 MFMAs) ----
        #pragma unroll
        for (int p = 0; p < 2; ++p) {
            #pragma unroll
            for (int ft = 0; ft < 8; ++ft) {
                const short8 va = *(const short8*)
                    (&Vs[(16*ft + ln15) * 64 + (((4*p + quad) ^ (ln15 & 7))) * 8]);
                O1t[0][ft] = __builtin_amdgcn_mfma_f32_16x16x32_bf16(va, p1f[0][p], O1t[0][ft], 0, 0, 0);
                O1t[1][ft] = __builtin_amdgcn_mfma_f32_16x16x32_bf16(va, p1f[1][p], O1t[1][ft], 0, 0, 0);
                O2t[0][ft] = __builtin_amdgcn_mfma_f32_16x16x32_bf16(va, p2f[0][p], O2t[0][ft], 0, 0, 0);
                O2t[1][ft] = __builtin_amdgcn_mfma_f32_16x16x32_bf16(va, p2f[1][p], O2t[1][ft], 0, 0, 0);
            }
        }
    }

    // ---- reductions: intra-wave l across quads, then cross-half via LDS ----
    #pragma unroll
    for (int g = 0; g < 2; ++g) {
        l1[g] += __shfl_xor(l1[g], 16); l1[g] += __shfl_xor(l1[g], 32);
        l2[g] += __shfl_xor(l2[g], 16); l2[g] += __shfl_xor(l2[g], 32);
    }

    float* comb = (float*)&smem[0][0][0];
    __syncthreads();   // all compute done, smem reusable
    if (half == 1) {
        if (quad == 0) {
            #pragma unroll
            for (int g = 0; g < 2; ++g) {
                comb[      qg*32 + g*16 + ln15] = l1[g];
                comb[128 + qg*32 + g*16 + ln15] = l2[g];
            }
        }
        #pragma unroll
        for (int g = 0; g < 2; ++g)
            #pragma unroll
            for (int ft = 0; ft < 8; ++ft)
                #pragma unroll
                for (int r = 0; r < 4; ++r)
                    comb[512 + (((g*8 + ft)*4 + r) * 256) + qg*64 + lane] = O1t[g][ft][r];
    }
    __syncthreads();
    if (half == 0) {
        #pragma unroll
        for (int g = 0; g < 2; ++g) {
            l1[g] += comb[      qg*32 + g*16 + ln15];
            l2[g] += comb[128 + qg*32 + g*16 + ln15];
        }
        #pragma unroll
        for (int g = 0; g < 2; ++g)
            #pragma unroll
            for (int ft = 0; ft < 8; ++ft)
                #pragma unroll
                for (int r = 0; r < 4; ++r)
                    O1t[g][ft][r] += comb[512 + (((g*8 + ft)*4 + r) * 256) + qg*64 + lane];
    }
    __syncthreads();
    if (half == 1) {
        #pragma unroll
        for (int g = 0; g < 2; ++g)
            #pragma unroll
            for (int ft = 0; ft < 8; ++ft)
                #pragma unroll
                for (int r = 0; r < 4; ++r)
                    comb[512 + (((g*8 + ft)*4 + r) * 256) + qg*64 + lane] = O2t[g][ft][r];
    }
    __syncthreads();
    if (half == 0) {
        #pragma unroll
        for (int g = 0; g < 2; ++g)
            #pragma unroll
            for (int ft = 0; ft < 8; ++ft)
                #pragma unroll
                for (int r = 0; r < 4; ++r)
                    O2t[g][ft][r] += comb[512 + (((g*8 + ft)*4 + r) * 256) + qg*64 + lane];

        // ---- epilogue: out = x + O1/l1 - s2*O2/l2, layout [B][F][T] ----
        const float s2h = s2g[h];
        float i1[2], i2[2];
        #pragma unroll
        for (int g = 0; g < 2; ++g) { i1[g] = 1.f / l1[g]; i2[g] = s2h / l2[g]; }
        const size_t obase = (size_t)b * F_DIM * T_DIM;
        const int f0 = h * HF;
        #pragma unroll
        for (int g = 0; g < 2; ++g) {
            const int t = q0 + qg*32 + g*16 + ln15;
            #pragma unroll
            for (int ft = 0; ft < 8; ++ft) {
                #pragma unroll
                for (int r = 0; r < 4; ++r) {
                    const int feat = 16*ft + 4*quad + r;
                    const size_t idx = obase + (size_t)(f0 + feat) * T_DIM + t;
                    out[idx] = x[idx] + O1t[g][ft][r] * i1[g] - O2t[g][ft][r] * i2[g];
                }
            }
        }
    }
}

extern "C" void kernel_launch(void* const* d_in, const int* in_sizes, int n_in,
                              void* d_out, int out_size, void* d_ws, size_t ws_size,
                              hipStream_t stream)
{
    const float* x  = (const float*)d_in[0];
    const float* Wq = (const float*)d_in[1];
    const float* bq = (const float*)d_in[2];
    const float* Wk = (const float*)d_in[3];
    const float* bk = (const float*)d_in[4];
    const float* Wv = (const float*)d_in[5];
    const float* bv = (const float*)d_in[6];
    const float* s2 = (const float*)d_in[7];
    float* out = (float*)d_out;

    const size_t per = (size_t)B_DIM * T_DIM * F_DIM;
    const size_t wsz = (size_t)F_DIM * F_DIM;
    unsigned short* xt  = (unsigned short*)d_ws;
    unsigned short* Wqb = xt + per;
    unsigned short* Wkb = Wqb + wsz;
    unsigned short* Wvb = Wkb + wsz;
    unsigned short* Qb  = Wvb + wsz;
    unsigned short* Kb  = Qb + per;
    unsigned short* Vtb = Kb + per;

    hipLaunchKernelGGL(prep_kernel, dim3(32, 8, 5), dim3(256), 0, stream,
                       x, Wq, Wk, Wv, xt, Wqb, Wkb, Wvb);

    hipLaunchKernelGGL(proj_kernel, dim3(16, 8, 12), dim3(256), 0, stream,
                       xt, Wqb, Wkb, Wvb, bq, bk, bv, Qb, Kb, Vtb);

    hipLaunchKernelGGL(attn_kernel, dim3(16, 4, 4), dim3(512), 0, stream,
                       Qb, Kb, Vtb, x, s2, out);
}

// Round 6
// 94.539 us; speedup vs baseline: 1.9669x; 1.1745x over previous
//
#include <hip/hip_runtime.h>
#include <math.h>

#define B_DIM 4
#define F_DIM 512
#define T_DIM 2048
#define H_DIM 4
#define HF    128

typedef __attribute__((ext_vector_type(8))) short short8;
typedef __attribute__((ext_vector_type(4))) float floatx4;

// round-half-up bf16 (2 inst)
__device__ __forceinline__ unsigned short f2bf(float f) {
    return (unsigned short)((__float_as_uint(f) + 0x8000u) >> 16);
}

// two floats -> packed bf16 pair: 2 adds + 1 v_perm_b32
__device__ __forceinline__ unsigned pkbf2(float a, float b) {
    const unsigned ua = __float_as_uint(a) + 0x8000u;
    const unsigned ub = __float_as_uint(b) + 0x8000u;
    return __builtin_amdgcn_perm(ub, ua, 0x07060302u);  // [ua.hi16 | ub.hi16]
}

__device__ __forceinline__ short8 pack8(const float* v) {
    union { unsigned u[4]; short8 s; } r;
    #pragma unroll
    for (int j = 0; j < 4; ++j) r.u[j] = pkbf2(v[2*j], v[2*j+1]);
    return r.s;
}

// direct-to-LDS 16B load: per-lane global src, wave-uniform LDS base + lane*16
__device__ __forceinline__ void gload16(const unsigned short* g, unsigned short* l) {
    __builtin_amdgcn_global_load_lds(
        (const __attribute__((address_space(1))) void*)g,
        (__attribute__((address_space(3))) void*)l, 16, 0, 0);
}

// ---------------- Kernel 0: prep ----------------
__global__ __launch_bounds__(256)
void prep_kernel(const float* __restrict__ x,
                 const float* __restrict__ Wq, const float* __restrict__ Wk,
                 const float* __restrict__ Wv,
                 unsigned short* __restrict__ xt,
                 unsigned short* __restrict__ Wqb, unsigned short* __restrict__ Wkb,
                 unsigned short* __restrict__ Wvb)
{
    const int tid = threadIdx.x;
    if (blockIdx.z < B_DIM) {
        const int b  = blockIdx.z;
        const int t0 = blockIdx.x * 64;
        const int f0 = blockIdx.y * 64;
        __shared__ float Ls[64][67];
        const float* __restrict__ xb = x + (size_t)b * F_DIM * T_DIM;
        #pragma unroll
        for (int it = 0; it < 4; ++it) {
            const int fr = (tid >> 4) + 16 * it;
            const int tc = (tid & 15) << 2;
            const float4 v = *(const float4*)(xb + (size_t)(f0 + fr) * T_DIM + t0 + tc);
            Ls[fr][tc+0] = v.x; Ls[fr][tc+1] = v.y; Ls[fr][tc+2] = v.z; Ls[fr][tc+3] = v.w;
        }
        __syncthreads();
        const int f8 = tid & 7;
        const int tb = tid >> 3;
        #pragma unroll
        for (int it2 = 0; it2 < 2; ++it2) {
            const int t = tb + 32 * it2;
            float v[8];
            #pragma unroll
            for (int j = 0; j < 8; ++j) v[j] = Ls[8*f8 + j][t];
            *(short8*)(xt + ((size_t)b * T_DIM + t0 + t) * F_DIM + f0 + 8*f8) = pack8(v);
        }
    } else {
        const int blockId = blockIdx.y * 32 + blockIdx.x;
        const int g0 = blockId * 256 + tid;
        const int perW = F_DIM * F_DIM / 8;
        for (int chunk = g0; chunk < 3 * perW; chunk += 65536) {
            const int wsel = chunk / perW;
            const int rem  = chunk - wsel * perW;
            const float* __restrict__ Ws = (wsel == 0) ? Wq : (wsel == 1) ? Wk : Wv;
            unsigned short* __restrict__ Wd = (wsel == 0) ? Wqb : (wsel == 1) ? Wkb : Wvb;
            float v[8];
            *(float4*)&v[0] = *(const float4*)(Ws + (size_t)rem * 8);
            *(float4*)&v[4] = *(const float4*)(Ws + (size_t)rem * 8 + 4);
            *(short8*)(Wd + (size_t)rem * 8) = pack8(v);
        }
    }
}

// ---------------- Kernel 1: merged QKV projection, BK=128 ----------------
#define ASTR 136   // 17 16B-granules per row (odd) -> all b128 accesses conflict-free

__global__ __launch_bounds__(256, 3)
void proj_kernel(const unsigned short* __restrict__ xt,
                 const unsigned short* __restrict__ Wqb,
                 const unsigned short* __restrict__ Wkb,
                 const unsigned short* __restrict__ Wvb,
                 const float* __restrict__ bq, const float* __restrict__ bk,
                 const float* __restrict__ bv,
                 unsigned short* __restrict__ Qb, unsigned short* __restrict__ Kb,
                 unsigned short* __restrict__ Vtb)
{
    __shared__ unsigned short As[128][ASTR];
    __shared__ unsigned short Bs[64][ASTR];

    const int tid  = threadIdx.x;
    const int w    = tid >> 6;
    const int lane = tid & 63;
    const int ln15 = lane & 15;
    const int quad = lane >> 4;

    // R11: XCD-chunked swizzle of the 128-block (x,y) plane (z untouched):
    // each XCD keeps one 64-row W panel L2-resident. Perf heuristic only.
    const int flat = blockIdx.x + 16 * blockIdx.y;       // 0..127
    const int fswz = (flat & 7) * 16 + (flat >> 3);      // bijective, 128%8==0
    const int bx   = fswz & 15;
    const int by   = fswz >> 4;

    const bool is_v = (blockIdx.z >= 8);
    int t0, fo0, b;
    const unsigned short *Asrc, *Bsrc;
    if (!is_v) {
        t0  = bx * 128;
        fo0 = by * 64;
        b   = blockIdx.z >> 1;
        Asrc = xt + (size_t)b * T_DIM * F_DIM + (size_t)t0 * F_DIM;
        Bsrc = ((blockIdx.z & 1) ? Wkb : Wqb) + (size_t)fo0 * F_DIM;
    } else {
        const int idx = fswz;                            // 0..127
        fo0 = (idx >> 5) * 128;
        t0  = (idx & 31) * 64;
        b   = blockIdx.z - 8;
        Asrc = Wvb + (size_t)fo0 * F_DIM;
        Bsrc = xt + (size_t)b * T_DIM * F_DIM + (size_t)t0 * F_DIM;
    }

    floatx4 acc[2][4];
    #pragma unroll
    for (int mi = 0; mi < 2; ++mi)
        #pragma unroll
        for (int nt = 0; nt < 4; ++nt) acc[mi][nt] = (floatx4){0.f,0.f,0.f,0.f};

    for (int f0 = 0; f0 < F_DIM; f0 += 128) {
        __syncthreads();
        #pragma unroll
        for (int it = 0; it < 8; ++it) {          // A: 128 rows x 16 chunks
            const int idx = tid + it * 256;
            const int r = idx >> 4, c = (idx & 15) * 8;
            *(short8*)&As[r][c] = *(const short8*)(Asrc + (size_t)r * F_DIM + f0 + c);
        }
        #pragma unroll
        for (int it = 0; it < 4; ++it) {          // B: 64 rows x 16 chunks
            const int idx = tid + it * 256;
            const int r = idx >> 4, c = (idx & 15) * 8;
            *(short8*)&Bs[r][c] = *(const short8*)(Bsrc + (size_t)r * F_DIM + f0 + c);
        }
        __syncthreads();
        #pragma unroll
        for (int ks = 0; ks < 4; ++ks) {
            short8 a[2], bb[4];
            a[0] = *(const short8*)&As[w*32      + ln15][ks*32 + quad*8];
            a[1] = *(const short8*)&As[w*32 + 16 + ln15][ks*32 + quad*8];
            #pragma unroll
            for (int nt = 0; nt < 4; ++nt)
                bb[nt] = *(const short8*)&Bs[16*nt + ln15][ks*32 + quad*8];
            #pragma unroll
            for (int mi = 0; mi < 2; ++mi)
                #pragma unroll
                for (int nt = 0; nt < 4; ++nt)
                    acc[mi][nt] = __builtin_amdgcn_mfma_f32_16x16x32_bf16(
                        a[mi], bb[nt], acc[mi][nt], 0, 0, 0);
        }
    }

    if (!is_v) {
        const int which = blockIdx.z & 1;
        const float* bias = which ? bk : bq;
        unsigned short* __restrict__ Out =
            (which ? Kb : Qb) + (size_t)b * T_DIM * F_DIM;
        // Q carries 1/sqrt(F/2) * log2(e) so attn can use exp2 (v_exp_f32 native)
        const float oscale = which ? 1.0f : 0.0625f * 1.4426950408889634f;
        float bn[4];
        #pragma unroll
        for (int nt = 0; nt < 4; ++nt) bn[nt] = bias[fo0 + 16*nt + ln15];
        const float pw[2] = {
            __uint_as_float((unsigned)(123 - ln15) << 23),   // 2^-(ln15+4)
            __uint_as_float((unsigned)(107 - ln15) << 23)    // 2^-(ln15+20)
        };
        #pragma unroll
        for (int mi = 0; mi < 2; ++mi) {
            #pragma unroll
            for (int r = 0; r < 4; ++r) {
                const int t = t0 + w*32 + 16*mi + quad*4 + r;
                unsigned short* rowp = Out + (size_t)t * F_DIM + fo0;
                #pragma unroll
                for (int pr = 0; pr < 2; ++pr) {
                    const int wi = 16*pr + ln15;
                    const float re = acc[mi][pr  ][r] + bn[pr];
                    const float im = acc[mi][pr+2][r] + bn[pr+2];
                    const float u = (float)t * pw[pr];
                    float sn, cs;
                    __sincosf(u, &sn, &cs);
                    rowp[wi]      = f2bf((re * sn - im * cs) * oscale);
                    rowp[wi + 32] = f2bf((re * cs + im * sn) * oscale);
                }
            }
        }
    } else {
        #pragma unroll
        for (int mi = 0; mi < 2; ++mi) {
            #pragma unroll
            for (int r = 0; r < 4; ++r) {
                const int fo = fo0 + w*32 + 16*mi + quad*4 + r;
                const float bvv = bv[fo];
                unsigned short* rowp = Vtb + ((size_t)b * F_DIM + fo) * T_DIM + t0;
                #pragma unroll
                for (int nt = 0; nt < 4; ++nt)
                    rowp[16*nt + ln15] = f2bf(acc[mi][nt][r] + bvv);
            }
        }
    }
}

// ---------------- Kernel 2: S^T MFMA flash attention, nq=32/wave -----------
// R12: verbatim restore of the Round-1 (R7) attn kernel — twice measured
// ~70 us, no spill. R8/R9/R10/R11 all showed that ANY mutation of this loop
// body (reorders, setprio, even FP reassociation of the l-sums) perturbs the
// scheduler/allocator past the 256-reg cliff into scratch spill (WRITE_SIZE
// 34-420 MB signatures). This schedule is the proven fit; do not touch.
__global__ __launch_bounds__(512, 2)
void attn_kernel(const unsigned short* __restrict__ Qb,
                 const unsigned short* __restrict__ Kb,
                 const unsigned short* __restrict__ Vtb,
                 const float* __restrict__ x,
                 const float* __restrict__ s2g,
                 float* __restrict__ out)
{
    __shared__ unsigned short smem[2][2][16384];   // [half][buf][K 8192 | V 8192] = 128 KB

    const int tid  = threadIdx.x;
    const int w8   = tid >> 6;
    const int half = w8 >> 2;
    const int qg   = w8 & 3;          // q-group index == staging slice index
    const int lane = tid & 63;
    const int ln15 = lane & 15;
    const int quad = lane >> 4;

    // XCD-chunked swizzle: 256 blocks, chunk 32 -> each XCD owns 2 (b,h) pairs
    const int flat = blockIdx.x + 16 * (blockIdx.y + 4 * blockIdx.z);
    const int swz  = (flat & 7) * 32 + (flat >> 3);
    const int q0 = (swz & 15) * 128;
    const int h  = (swz >> 4) & 3;
    const int b  = swz >> 6;

    const int kbase = half << 10;   // 0 or 1024

    const unsigned short* __restrict__ Qg =
        Qb + ((size_t)b * T_DIM + q0 + qg * 32) * F_DIM + h * HF;
    const unsigned short* __restrict__ Kg =
        Kb + (size_t)b * T_DIM * F_DIM + h * HF;
    const unsigned short* __restrict__ Vg =
        Vtb + ((size_t)b * F_DIM + h * HF) * T_DIM;

    // Per-lane inverse-swizzled global source offsets so that linear
    // global_load_lds (uniform base + lane*16) reproduces the swizzled layout:
    //   K LDS: dest row rd holds source row r=inv(rd), col granule cd = c^(rd&15)
    //     forward perm: rp = (r&32)|((r&4)<<2)|((r&24)>>1)|(r&3)
    //     inverse:      r  = (rd&32)|((rd&12)<<1)|((rd&16)>>2)|(rd&3)
    //   V LDS: dest row rd = feat, col granule cd = c^(rd&7)
    int koff[4], voff[4];
    #pragma unroll
    for (int it = 0; it < 4; ++it) {
        const int m = qg * 4 + it;
        {
            const int rd = 4 * m + (lane >> 4);
            const int r  = (rd & 32) | ((rd & 12) << 1) | ((rd & 16) >> 2) | (rd & 3);
            const int c  = (lane & 15) ^ (rd & 15);
            koff[it] = r * F_DIM + c * 8;
        }
        {
            const int rd = 8 * m + (lane >> 3);
            const int c  = (lane & 7) ^ (rd & 7);
            voff[it] = rd * T_DIM + c * 8;
        }
    }

    auto stage = [&](int buf, int k) {
        unsigned short* Kd = &smem[half][buf][0]    + qg * 2048;
        unsigned short* Vd = &smem[half][buf][8192] + qg * 2048;
        const unsigned short* Kp = Kg + (size_t)(kbase + k) * F_DIM;
        const unsigned short* Vp = Vg + (kbase + k);
        #pragma unroll
        for (int it = 0; it < 4; ++it) {
            gload16(Kp + koff[it], Kd + it * 512);
            gload16(Vp + voff[it], Vd + it * 512);
        }
    };

    // Q B-frags (resident): B[k=feat][n=q=ln15], two 16-q groups
    short8 qa[2][4];
    #pragma unroll
    for (int g = 0; g < 2; ++g)
        #pragma unroll
        for (int c = 0; c < 4; ++c)
            qa[g][c] = *(const short8*)(Qg + (size_t)(g * 16 + ln15) * F_DIM + quad * 8 + 32 * c);

    floatx4 O1t[2][8], O2t[2][8];
    #pragma unroll
    for (int g = 0; g < 2; ++g)
        #pragma unroll
        for (int ft = 0; ft < 8; ++ft) {
            O1t[g][ft] = (floatx4){0.f, 0.f, 0.f, 0.f};
            O2t[g][ft] = (floatx4){0.f, 0.f, 0.f, 0.f};
        }
    float l1[2] = {0.f, 0.f}, l2[2] = {0.f, 0.f};

    stage(0, 0);   // prologue: tile 0 -> buf 0

    for (int k0 = 0; k0 < 1024; k0 += 64) {
        asm volatile("s_waitcnt vmcnt(0)" ::: "memory");  // own tile-k0 DMA done
        __syncthreads();                                   // everyone's tile in LDS
        const int buf = (k0 >> 6) & 1;
        if (k0 + 64 < 1024) stage(buf ^ 1, k0 + 64);       // in flight across compute

        const unsigned short* Ks = &smem[half][buf][0];
        const unsigned short* Vs = &smem[half][buf][8192];

        // ---- scores S^T[k][q] + no-max softmax numerators p = 2^S ----
        short8 p1f[2][2], p2f[2][2];
        #pragma unroll
        for (int tp = 0; tp < 2; ++tp) {
            float e1[2][8], e2[2][8];
            #pragma unroll
            for (int tt = 0; tt < 2; ++tt) {
                const int t = tp * 2 + tt;
                const unsigned short* krow = &Ks[(16 * t + ln15) * 128];
                const short8 k0f = *(const short8*)(krow + ((quad     ) ^ ln15) * 8);
                const short8 k1f = *(const short8*)(krow + ((quad +  4) ^ ln15) * 8);
                const short8 k2f = *(const short8*)(krow + ((quad +  8) ^ ln15) * 8);
                const short8 k3f = *(const short8*)(krow + ((quad + 12) ^ ln15) * 8);
                #pragma unroll
                for (int g = 0; g < 2; ++g) {
                    floatx4 z = (floatx4){0.f, 0.f, 0.f, 0.f};
                    floatx4 s = __builtin_amdgcn_mfma_f32_16x16x32_bf16(k0f, qa[g][0], z, 0, 0, 0);
                    s         = __builtin_amdgcn_mfma_f32_16x16x32_bf16(k1f, qa[g][1], s, 0, 0, 0);
                    floatx4 u = __builtin_amdgcn_mfma_f32_16x16x32_bf16(k2f, qa[g][2], z, 0, 0, 0);
                    u         = __builtin_amdgcn_mfma_f32_16x16x32_bf16(k3f, qa[g][3], u, 0, 0, 0);
                    #pragma unroll
                    for (int r = 0; r < 4; ++r) {
                        e1[g][tt*4 + r] = __builtin_amdgcn_exp2f(s[r]);
                        e2[g][tt*4 + r] = __builtin_amdgcn_exp2f(u[r]);
                    }
                }
            }
            #pragma unroll
            for (int g = 0; g < 2; ++g) {
                #pragma unroll
                for (int j = 0; j < 8; ++j) { l1[g] += e1[g][j]; l2[g] += e2[g][j]; }
                p1f[g][tp] = pack8(&e1[g][0]);
                p2f[g][tp] = pack8(&e2[g][0]);
            }
        }

        // ---- PV: O^T += V^T . P^T (each va read feeds 4 MFMAs) ----
        #pragma unroll
        for (int p = 0; p < 2; ++p) {
            #pragma unroll
            for (int ft = 0; ft < 8; ++ft) {
                const short8 va = *(const short8*)
                    (&Vs[(16*ft + ln15) * 64 + (((4*p + quad) ^ (ln15 & 7))) * 8]);
                O1t[0][ft] = __builtin_amdgcn_mfma_f32_16x16x32_bf16(va, p1f[0][p], O1t[0][ft], 0, 0, 0);
                O1t[1][ft] = __builtin_amdgcn_mfma_f32_16x16x32_bf16(va, p1f[1][p], O1t[1][ft], 0, 0, 0);
                O2t[0][ft] = __builtin_amdgcn_mfma_f32_16x16x32_bf16(va, p2f[0][p], O2t[0][ft], 0, 0, 0);
                O2t[1][ft] = __builtin_amdgcn_mfma_f32_16x16x32_bf16(va, p2f[1][p], O2t[1][ft], 0, 0, 0);
            }
        }
    }

    // ---- reductions: intra-wave l across quads, then cross-half via LDS ----
    #pragma unroll
    for (int g = 0; g < 2; ++g) {
        l1[g] += __shfl_xor(l1[g], 16); l1[g] += __shfl_xor(l1[g], 32);
        l2[g] += __shfl_xor(l2[g], 16); l2[g] += __shfl_xor(l2[g], 32);
    }

    float* comb = (float*)&smem[0][0][0];
    __syncthreads();   // all compute done, smem reusable
    if (half == 1) {
        if (quad == 0) {
            #pragma unroll
            for (int g = 0; g < 2; ++g) {
                comb[      qg*32 + g*16 + ln15] = l1[g];
                comb[128 + qg*32 + g*16 + ln15] = l2[g];
            }
        }
        #pragma unroll
        for (int g = 0; g < 2; ++g)
            #pragma unroll
            for (int ft = 0; ft < 8; ++ft)
                #pragma unroll
                for (int r = 0; r < 4; ++r)
                    comb[512 + (((g*8 + ft)*4 + r) * 256) + qg*64 + lane] = O1t[g][ft][r];
    }
    __syncthreads();
    if (half == 0) {
        #pragma unroll
        for (int g = 0; g < 2; ++g) {
            l1[g] += comb[      qg*32 + g*16 + ln15];
            l2[g] += comb[128 + qg*32 + g*16 + ln15];
        }
        #pragma unroll
        for (int g = 0; g < 2; ++g)
            #pragma unroll
            for (int ft = 0; ft < 8; ++ft)
                #pragma unroll
                for (int r = 0; r < 4; ++r)
                    O1t[g][ft][r] += comb[512 + (((g*8 + ft)*4 + r) * 256) + qg*64 + lane];
    }
    __syncthreads();
    if (half == 1) {
        #pragma unroll
        for (int g = 0; g < 2; ++g)
            #pragma unroll
            for (int ft = 0; ft < 8; ++ft)
                #pragma unroll
                for (int r = 0; r < 4; ++r)
                    comb[512 + (((g*8 + ft)*4 + r) * 256) + qg*64 + lane] = O2t[g][ft][r];
    }
    __syncthreads();
    if (half == 0) {
        #pragma unroll
        for (int g = 0; g < 2; ++g)
            #pragma unroll
            for (int ft = 0; ft < 8; ++ft)
                #pragma unroll
                for (int r = 0; r < 4; ++r)
                    O2t[g][ft][r] += comb[512 + (((g*8 + ft)*4 + r) * 256) + qg*64 + lane];

        // ---- epilogue: out = x + O1/l1 - s2*O2/l2, layout [B][F][T] ----
        const float s2h = s2g[h];
        float i1[2], i2[2];
        #pragma unroll
        for (int g = 0; g < 2; ++g) { i1[g] = 1.f / l1[g]; i2[g] = s2h / l2[g]; }
        const size_t obase = (size_t)b * F_DIM * T_DIM;
        const int f0 = h * HF;
        #pragma unroll
        for (int g = 0; g < 2; ++g) {
            const int t = q0 + qg*32 + g*16 + ln15;
            #pragma unroll
            for (int ft = 0; ft < 8; ++ft) {
                #pragma unroll
                for (int r = 0; r < 4; ++r) {
                    const int feat = 16*ft + 4*quad + r;
                    const size_t idx = obase + (size_t)(f0 + feat) * T_DIM + t;
                    out[idx] = x[idx] + O1t[g][ft][r] * i1[g] - O2t[g][ft][r] * i2[g];
                }
            }
        }
    }
}

extern "C" void kernel_launch(void* const* d_in, const int* in_sizes, int n_in,
                              void* d_out, int out_size, void* d_ws, size_t ws_size,
                              hipStream_t stream)
{
    const float* x  = (const float*)d_in[0];
    const float* Wq = (const float*)d_in[1];
    const float* bq = (const float*)d_in[2];
    const float* Wk = (const float*)d_in[3];
    const float* bk = (const float*)d_in[4];
    const float* Wv = (const float*)d_in[5];
    const float* bv = (const float*)d_in[6];
    const float* s2 = (const float*)d_in[7];
    float* out = (float*)d_out;

    const size_t per = (size_t)B_DIM * T_DIM * F_DIM;
    const size_t wsz = (size_t)F_DIM * F_DIM;
    unsigned short* xt  = (unsigned short*)d_ws;
    unsigned short* Wqb = xt + per;
    unsigned short* Wkb = Wqb + wsz;
    unsigned short* Wvb = Wkb + wsz;
    unsigned short* Qb  = Wvb + wsz;
    unsigned short* Kb  = Qb + per;
    unsigned short* Vtb = Kb + per;

    hipLaunchKernelGGL(prep_kernel, dim3(32, 8, 5), dim3(256), 0, stream,
                       x, Wq, Wk, Wv, xt, Wqb, Wkb, Wvb);

    hipLaunchKernelGGL(proj_kernel, dim3(16, 8, 12), dim3(256), 0, stream,
                       xt, Wqb, Wkb, Wvb, bq, bk, bv, Qb, Kb, Vtb);

    hipLaunchKernelGGL(attn_kernel, dim3(16, 4, 4), dim3(512), 0, stream,
                       Qb, Kb, Vtb, x, s2, out);
}

// Round 7
// 92.952 us; speedup vs baseline: 2.0005x; 1.0171x over previous
//
#include <hip/hip_runtime.h>
#include <math.h>

#define B_DIM 4
#define F_DIM 512
#define T_DIM 2048
#define H_DIM 4
#define HF    128

typedef __attribute__((ext_vector_type(8))) short short8;
typedef __attribute__((ext_vector_type(4))) float floatx4;

// round-half-up bf16 (2 inst)
__device__ __forceinline__ unsigned short f2bf(float f) {
    return (unsigned short)((__float_as_uint(f) + 0x8000u) >> 16);
}

// two floats -> packed bf16 pair: 2 adds + 1 v_perm_b32
__device__ __forceinline__ unsigned pkbf2(float a, float b) {
    const unsigned ua = __float_as_uint(a) + 0x8000u;
    const unsigned ub = __float_as_uint(b) + 0x8000u;
    return __builtin_amdgcn_perm(ub, ua, 0x07060302u);  // [ua.hi16 | ub.hi16]
}

__device__ __forceinline__ short8 pack8(const float* v) {
    union { unsigned u[4]; short8 s; } r;
    #pragma unroll
    for (int j = 0; j < 4; ++j) r.u[j] = pkbf2(v[2*j], v[2*j+1]);
    return r.s;
}

// direct-to-LDS 16B load: per-lane global src, wave-uniform LDS base + lane*16
__device__ __forceinline__ void gload16(const unsigned short* g, unsigned short* l) {
    __builtin_amdgcn_global_load_lds(
        (const __attribute__((address_space(1))) void*)g,
        (__attribute__((address_space(3))) void*)l, 16, 0, 0);
}

// ---------------- Kernel 0: prep ----------------
__global__ __launch_bounds__(256)
void prep_kernel(const float* __restrict__ x,
                 const float* __restrict__ Wq, const float* __restrict__ Wk,
                 const float* __restrict__ Wv,
                 unsigned short* __restrict__ xt,
                 unsigned short* __restrict__ Wqb, unsigned short* __restrict__ Wkb,
                 unsigned short* __restrict__ Wvb)
{
    const int tid = threadIdx.x;
    if (blockIdx.z < B_DIM) {
        const int b  = blockIdx.z;
        const int t0 = blockIdx.x * 64;
        const int f0 = blockIdx.y * 64;
        __shared__ float Ls[64][67];
        const float* __restrict__ xb = x + (size_t)b * F_DIM * T_DIM;
        #pragma unroll
        for (int it = 0; it < 4; ++it) {
            const int fr = (tid >> 4) + 16 * it;
            const int tc = (tid & 15) << 2;
            const float4 v = *(const float4*)(xb + (size_t)(f0 + fr) * T_DIM + t0 + tc);
            Ls[fr][tc+0] = v.x; Ls[fr][tc+1] = v.y; Ls[fr][tc+2] = v.z; Ls[fr][tc+3] = v.w;
        }
        __syncthreads();
        const int f8 = tid & 7;
        const int tb = tid >> 3;
        #pragma unroll
        for (int it2 = 0; it2 < 2; ++it2) {
            const int t = tb + 32 * it2;
            float v[8];
            #pragma unroll
            for (int j = 0; j < 8; ++j) v[j] = Ls[8*f8 + j][t];
            *(short8*)(xt + ((size_t)b * T_DIM + t0 + t) * F_DIM + f0 + 8*f8) = pack8(v);
        }
    } else {
        const int blockId = blockIdx.y * 32 + blockIdx.x;
        const int g0 = blockId * 256 + tid;
        const int perW = F_DIM * F_DIM / 8;
        for (int chunk = g0; chunk < 3 * perW; chunk += 65536) {
            const int wsel = chunk / perW;
            const int rem  = chunk - wsel * perW;
            const float* __restrict__ Ws = (wsel == 0) ? Wq : (wsel == 1) ? Wk : Wv;
            unsigned short* __restrict__ Wd = (wsel == 0) ? Wqb : (wsel == 1) ? Wkb : Wvb;
            float v[8];
            *(float4*)&v[0] = *(const float4*)(Ws + (size_t)rem * 8);
            *(float4*)&v[4] = *(const float4*)(Ws + (size_t)rem * 8 + 4);
            *(short8*)(Wd + (size_t)rem * 8) = pack8(v);
        }
    }
}

// ---------------- Kernel 1: merged QKV projection, BK=128 ----------------
// R13: staging via global_load_lds (width 16) with XOR-granule swizzle
// g' = g ^ (r&15) on a linear [r][128] LDS layout (replaces the ASTR=136 pad,
// which gload_lds's linear dest cannot target). Per-lane inverse-swizzled
// source offsets precomputed once — the exact pattern proven in attn.
// Removes the global->VGPR->ds_write round trip and its address VALU
// (Common-mistake #1; m193 isolated +67% on staging-bound GEMM fraction).
__global__ __launch_bounds__(256, 3)
void proj_kernel(const unsigned short* __restrict__ xt,
                 const unsigned short* __restrict__ Wqb,
                 const unsigned short* __restrict__ Wkb,
                 const unsigned short* __restrict__ Wvb,
                 const float* __restrict__ bq, const float* __restrict__ bk,
                 const float* __restrict__ bv,
                 unsigned short* __restrict__ Qb, unsigned short* __restrict__ Kb,
                 unsigned short* __restrict__ Vtb)
{
    __shared__ unsigned short As[128][128];   // 32 KB, linear rows, XOR-swizzled granules
    __shared__ unsigned short Bs[64][128];    // 16 KB

    const int tid  = threadIdx.x;
    const int w    = tid >> 6;
    const int lane = tid & 63;
    const int ln15 = lane & 15;
    const int quad = lane >> 4;

    // XCD-chunked swizzle of the 128-block (x,y) plane (z untouched).
    const int flat = blockIdx.x + 16 * blockIdx.y;       // 0..127
    const int fswz = (flat & 7) * 16 + (flat >> 3);      // bijective, 128%8==0
    const int bx   = fswz & 15;
    const int by   = fswz >> 4;

    const bool is_v = (blockIdx.z >= 8);
    int t0, fo0, b;
    const unsigned short *Asrc, *Bsrc;
    if (!is_v) {
        t0  = bx * 128;
        fo0 = by * 64;
        b   = blockIdx.z >> 1;
        Asrc = xt + (size_t)b * T_DIM * F_DIM + (size_t)t0 * F_DIM;
        Bsrc = ((blockIdx.z & 1) ? Wkb : Wqb) + (size_t)fo0 * F_DIM;
    } else {
        const int idx = fswz;                            // 0..127
        fo0 = (idx >> 5) * 128;
        t0  = (idx & 31) * 64;
        b   = blockIdx.z - 8;
        Asrc = Wvb + (size_t)fo0 * F_DIM;
        Bsrc = xt + (size_t)b * T_DIM * F_DIM + (size_t)t0 * F_DIM;
    }

    // Per-lane inverse-swizzled source offsets (granule = 8 shorts = 16 B).
    // Dest granule d -> (rd = d>>4, cd = d&15); source granule g = cd ^ (rd&15).
    int aoff[8], boff[4];
    #pragma unroll
    for (int it = 0; it < 8; ++it) {
        const int rd = w * 32 + it * 4 + (lane >> 4);
        const int g  = (lane & 15) ^ (rd & 15);
        aoff[it] = rd * F_DIM + g * 8;
    }
    #pragma unroll
    for (int it = 0; it < 4; ++it) {
        const int rd = w * 16 + it * 4 + (lane >> 4);
        const int g  = (lane & 15) ^ (rd & 15);
        boff[it] = rd * F_DIM + g * 8;
    }

    floatx4 acc[2][4];
    #pragma unroll
    for (int mi = 0; mi < 2; ++mi)
        #pragma unroll
        for (int nt = 0; nt < 4; ++nt) acc[mi][nt] = (floatx4){0.f,0.f,0.f,0.f};

    for (int f0 = 0; f0 < F_DIM; f0 += 128) {
        __syncthreads();                     // previous compute's reads done
        #pragma unroll
        for (int it = 0; it < 8; ++it)       // A: wave w stages rows [w*32, w*32+32)
            gload16(Asrc + aoff[it] + f0, &As[w * 32 + it * 4][0]);
        #pragma unroll
        for (int it = 0; it < 4; ++it)       // B: wave w stages rows [w*16, w*16+16)
            gload16(Bsrc + boff[it] + f0, &Bs[w * 16 + it * 4][0]);
        asm volatile("s_waitcnt vmcnt(0)" ::: "memory");
        __syncthreads();                     // tiles visible
        #pragma unroll
        for (int ks = 0; ks < 4; ++ks) {
            short8 a[2], bb[4];
            #pragma unroll
            for (int mi = 0; mi < 2; ++mi) {
                const int r = w * 32 + 16 * mi + ln15;
                a[mi] = *(const short8*)&As[r][(((ks * 4 + quad) ^ (r & 15))) * 8];
            }
            #pragma unroll
            for (int nt = 0; nt < 4; ++nt) {
                const int r = 16 * nt + ln15;
                bb[nt] = *(const short8*)&Bs[r][(((ks * 4 + quad) ^ (r & 15))) * 8];
            }
            #pragma unroll
            for (int mi = 0; mi < 2; ++mi)
                #pragma unroll
                for (int nt = 0; nt < 4; ++nt)
                    acc[mi][nt] = __builtin_amdgcn_mfma_f32_16x16x32_bf16(
                        a[mi], bb[nt], acc[mi][nt], 0, 0, 0);
        }
    }

    if (!is_v) {
        const int which = blockIdx.z & 1;
        const float* bias = which ? bk : bq;
        unsigned short* __restrict__ Out =
            (which ? Kb : Qb) + (size_t)b * T_DIM * F_DIM;
        // Q carries 1/sqrt(F/2) * log2(e) so attn can use exp2 (v_exp_f32 native)
        const float oscale = which ? 1.0f : 0.0625f * 1.4426950408889634f;
        float bn[4];
        #pragma unroll
        for (int nt = 0; nt < 4; ++nt) bn[nt] = bias[fo0 + 16*nt + ln15];
        const float pw[2] = {
            __uint_as_float((unsigned)(123 - ln15) << 23),   // 2^-(ln15+4)
            __uint_as_float((unsigned)(107 - ln15) << 23)    // 2^-(ln15+20)
        };
        #pragma unroll
        for (int mi = 0; mi < 2; ++mi) {
            #pragma unroll
            for (int r = 0; r < 4; ++r) {
                const int t = t0 + w*32 + 16*mi + quad*4 + r;
                unsigned short* rowp = Out + (size_t)t * F_DIM + fo0;
                #pragma unroll
                for (int pr = 0; pr < 2; ++pr) {
                    const int wi = 16*pr + ln15;
                    const float re = acc[mi][pr  ][r] + bn[pr];
                    const float im = acc[mi][pr+2][r] + bn[pr+2];
                    const float u = (float)t * pw[pr];
                    float sn, cs;
                    __sincosf(u, &sn, &cs);
                    rowp[wi]      = f2bf((re * sn - im * cs) * oscale);
                    rowp[wi + 32] = f2bf((re * cs + im * sn) * oscale);
                }
            }
        }
    } else {
        #pragma unroll
        for (int mi = 0; mi < 2; ++mi) {
            #pragma unroll
            for (int r = 0; r < 4; ++r) {
                const int fo = fo0 + w*32 + 16*mi + quad*4 + r;
                const float bvv = bv[fo];
                unsigned short* rowp = Vtb + ((size_t)b * F_DIM + fo) * T_DIM + t0;
                #pragma unroll
                for (int nt = 0; nt < 4; ++nt)
                    rowp[16*nt + ln15] = f2bf(acc[mi][nt][r] + bvv);
            }
        }
    }
}

// ---------------- Kernel 2: S^T MFMA flash attention, nq=32/wave -----------
// R12/R13: verbatim Round-1 (R7) attn kernel — twice measured ~70 us, no
// spill. R8-R11 showed ANY mutation of this loop body (reorders, setprio,
// even FP reassociation) tips the allocator past the 256-reg cliff into
// scratch spill. This schedule is the proven fit; do not touch.
__global__ __launch_bounds__(512, 2)
void attn_kernel(const unsigned short* __restrict__ Qb,
                 const unsigned short* __restrict__ Kb,
                 const unsigned short* __restrict__ Vtb,
                 const float* __restrict__ x,
                 const float* __restrict__ s2g,
                 float* __restrict__ out)
{
    __shared__ unsigned short smem[2][2][16384];   // [half][buf][K 8192 | V 8192] = 128 KB

    const int tid  = threadIdx.x;
    const int w8   = tid >> 6;
    const int half = w8 >> 2;
    const int qg   = w8 & 3;          // q-group index == staging slice index
    const int lane = tid & 63;
    const int ln15 = lane & 15;
    const int quad = lane >> 4;

    // XCD-chunked swizzle: 256 blocks, chunk 32 -> each XCD owns 2 (b,h) pairs
    const int flat = blockIdx.x + 16 * (blockIdx.y + 4 * blockIdx.z);
    const int swz  = (flat & 7) * 32 + (flat >> 3);
    const int q0 = (swz & 15) * 128;
    const int h  = (swz >> 4) & 3;
    const int b  = swz >> 6;

    const int kbase = half << 10;   // 0 or 1024

    const unsigned short* __restrict__ Qg =
        Qb + ((size_t)b * T_DIM + q0 + qg * 32) * F_DIM + h * HF;
    const unsigned short* __restrict__ Kg =
        Kb + (size_t)b * T_DIM * F_DIM + h * HF;
    const unsigned short* __restrict__ Vg =
        Vtb + ((size_t)b * F_DIM + h * HF) * T_DIM;

    // Per-lane inverse-swizzled global source offsets so that linear
    // global_load_lds (uniform base + lane*16) reproduces the swizzled layout:
    //   K LDS: dest row rd holds source row r=inv(rd), col granule cd = c^(rd&15)
    //     forward perm: rp = (r&32)|((r&4)<<2)|((r&24)>>1)|(r&3)
    //     inverse:      r  = (rd&32)|((rd&12)<<1)|((rd&16)>>2)|(rd&3)
    //   V LDS: dest row rd = feat, col granule cd = c^(rd&7)
    int koff[4], voff[4];
    #pragma unroll
    for (int it = 0; it < 4; ++it) {
        const int m = qg * 4 + it;
        {
            const int rd = 4 * m + (lane >> 4);
            const int r  = (rd & 32) | ((rd & 12) << 1) | ((rd & 16) >> 2) | (rd & 3);
            const int c  = (lane & 15) ^ (rd & 15);
            koff[it] = r * F_DIM + c * 8;
        }
        {
            const int rd = 8 * m + (lane >> 3);
            const int c  = (lane & 7) ^ (rd & 7);
            voff[it] = rd * T_DIM + c * 8;
        }
    }

    auto stage = [&](int buf, int k) {
        unsigned short* Kd = &smem[half][buf][0]    + qg * 2048;
        unsigned short* Vd = &smem[half][buf][8192] + qg * 2048;
        const unsigned short* Kp = Kg + (size_t)(kbase + k) * F_DIM;
        const unsigned short* Vp = Vg + (kbase + k);
        #pragma unroll
        for (int it = 0; it < 4; ++it) {
            gload16(Kp + koff[it], Kd + it * 512);
            gload16(Vp + voff[it], Vd + it * 512);
        }
    };

    // Q B-frags (resident): B[k=feat][n=q=ln15], two 16-q groups
    short8 qa[2][4];
    #pragma unroll
    for (int g = 0; g < 2; ++g)
        #pragma unroll
        for (int c = 0; c < 4; ++c)
            qa[g][c] = *(const short8*)(Qg + (size_t)(g * 16 + ln15) * F_DIM + quad * 8 + 32 * c);

    floatx4 O1t[2][8], O2t[2][8];
    #pragma unroll
    for (int g = 0; g < 2; ++g)
        #pragma unroll
        for (int ft = 0; ft < 8; ++ft) {
            O1t[g][ft] = (floatx4){0.f, 0.f, 0.f, 0.f};
            O2t[g][ft] = (floatx4){0.f, 0.f, 0.f, 0.f};
        }
    float l1[2] = {0.f, 0.f}, l2[2] = {0.f, 0.f};

    stage(0, 0);   // prologue: tile 0 -> buf 0

    for (int k0 = 0; k0 < 1024; k0 += 64) {
        asm volatile("s_waitcnt vmcnt(0)" ::: "memory");  // own tile-k0 DMA done
        __syncthreads();                                   // everyone's tile in LDS
        const int buf = (k0 >> 6) & 1;
        if (k0 + 64 < 1024) stage(buf ^ 1, k0 + 64);       // in flight across compute

        const unsigned short* Ks = &smem[half][buf][0];
        const unsigned short* Vs = &smem[half][buf][8192];

        // ---- scores S^T[k][q] + no-max softmax numerators p = 2^S ----
        short8 p1f[2][2], p2f[2][2];
        #pragma unroll
        for (int tp = 0; tp < 2; ++tp) {
            float e1[2][8], e2[2][8];
            #pragma unroll
            for (int tt = 0; tt < 2; ++tt) {
                const int t = tp * 2 + tt;
                const unsigned short* krow = &Ks[(16 * t + ln15) * 128];
                const short8 k0f = *(const short8*)(krow + ((quad     ) ^ ln15) * 8);
                const short8 k1f = *(const short8*)(krow + ((quad +  4) ^ ln15) * 8);
                const short8 k2f = *(const short8*)(krow + ((quad +  8) ^ ln15) * 8);
                const short8 k3f = *(const short8*)(krow + ((quad + 12) ^ ln15) * 8);
                #pragma unroll
                for (int g = 0; g < 2; ++g) {
                    floatx4 z = (floatx4){0.f, 0.f, 0.f, 0.f};
                    floatx4 s = __builtin_amdgcn_mfma_f32_16x16x32_bf16(k0f, qa[g][0], z, 0, 0, 0);
                    s         = __builtin_amdgcn_mfma_f32_16x16x32_bf16(k1f, qa[g][1], s, 0, 0, 0);
                    floatx4 u = __builtin_amdgcn_mfma_f32_16x16x32_bf16(k2f, qa[g][2], z, 0, 0, 0);
                    u         = __builtin_amdgcn_mfma_f32_16x16x32_bf16(k3f, qa[g][3], u, 0, 0, 0);
                    #pragma unroll
                    for (int r = 0; r < 4; ++r) {
                        e1[g][tt*4 + r] = __builtin_amdgcn_exp2f(s[r]);
                        e2[g][tt*4 + r] = __builtin_amdgcn_exp2f(u[r]);
                    }
                }
            }
            #pragma unroll
            for (int g = 0; g < 2; ++g) {
                #pragma unroll
                for (int j = 0; j < 8; ++j) { l1[g] += e1[g][j]; l2[g] += e2[g][j]; }
                p1f[g][tp] = pack8(&e1[g][0]);
                p2f[g][tp] = pack8(&e2[g][0]);
            }
        }

        // ---- PV: O^T += V^T . P^T (each va read feeds 4 MFMAs) ----
        #pragma unroll
        for (int p = 0; p < 2; ++p) {
            #pragma unroll
            for (int ft = 0; ft < 8; ++ft) {
                const short8 va = *(const short8*)
                    (&Vs[(16*ft + ln15) * 64 + (((4*p + quad) ^ (ln15 & 7))) * 8]);
                O1t[0][ft] = __builtin_amdgcn_mfma_f32_16x16x32_bf16(va, p1f[0][p], O1t[0][ft], 0, 0, 0);
                O1t[1][ft] = __builtin_amdgcn_mfma_f32_16x16x32_bf16(va, p1f[1][p], O1t[1][ft], 0, 0, 0);
                O2t[0][ft] = __builtin_amdgcn_mfma_f32_16x16x32_bf16(va, p2f[0][p], O2t[0][ft], 0, 0, 0);
                O2t[1][ft] = __builtin_amdgcn_mfma_f32_16x16x32_bf16(va, p2f[1][p], O2t[1][ft], 0, 0, 0);
            }
        }
    }

    // ---- reductions: intra-wave l across quads, then cross-half via LDS ----
    #pragma unroll
    for (int g = 0; g < 2; ++g) {
        l1[g] += __shfl_xor(l1[g], 16); l1[g] += __shfl_xor(l1[g], 32);
        l2[g] += __shfl_xor(l2[g], 16); l2[g] += __shfl_xor(l2[g], 32);
    }

    float* comb = (float*)&smem[0][0][0];
    __syncthreads();   // all compute done, smem reusable
    if (half == 1) {
        if (quad == 0) {
            #pragma unroll
            for (int g = 0; g < 2; ++g) {
                comb[      qg*32 + g*16 + ln15] = l1[g];
                comb[128 + qg*32 + g*16 + ln15] = l2[g];
            }
        }
        #pragma unroll
        for (int g = 0; g < 2; ++g)
            #pragma unroll
            for (int ft = 0; ft < 8; ++ft)
                #pragma unroll
                for (int r = 0; r < 4; ++r)
                    comb[512 + (((g*8 + ft)*4 + r) * 256) + qg*64 + lane] = O1t[g][ft][r];
    }
    __syncthreads();
    if (half == 0) {
        #pragma unroll
        for (int g = 0; g < 2; ++g) {
            l1[g] += comb[      qg*32 + g*16 + ln15];
            l2[g] += comb[128 + qg*32 + g*16 + ln15];
        }
        #pragma unroll
        for (int g = 0; g < 2; ++g)
            #pragma unroll
            for (int ft = 0; ft < 8; ++ft)
                #pragma unroll
                for (int r = 0; r < 4; ++r)
                    O1t[g][ft][r] += comb[512 + (((g*8 + ft)*4 + r) * 256) + qg*64 + lane];
    }
    __syncthreads();
    if (half == 1) {
        #pragma unroll
        for (int g = 0; g < 2; ++g)
            #pragma unroll
            for (int ft = 0; ft < 8; ++ft)
                #pragma unroll
                for (int r = 0; r < 4; ++r)
                    comb[512 + (((g*8 + ft)*4 + r) * 256) + qg*64 + lane] = O2t[g][ft][r];
    }
    __syncthreads();
    if (half == 0) {
        #pragma unroll
        for (int g = 0; g < 2; ++g)
            #pragma unroll
            for (int ft = 0; ft < 8; ++ft)
                #pragma unroll
                for (int r = 0; r < 4; ++r)
                    O2t[g][ft][r] += comb[512 + (((g*8 + ft)*4 + r) * 256) + qg*64 + lane];

        // ---- epilogue: out = x + O1/l1 - s2*O2/l2, layout [B][F][T] ----
        const float s2h = s2g[h];
        float i1[2], i2[2];
        #pragma unroll
        for (int g = 0; g < 2; ++g) { i1[g] = 1.f / l1[g]; i2[g] = s2h / l2[g]; }
        const size_t obase = (size_t)b * F_DIM * T_DIM;
        const int f0 = h * HF;
        #pragma unroll
        for (int g = 0; g < 2; ++g) {
            const int t = q0 + qg*32 + g*16 + ln15;
            #pragma unroll
            for (int ft = 0; ft < 8; ++ft) {
                #pragma unroll
                for (int r = 0; r < 4; ++r) {
                    const int feat = 16*ft + 4*quad + r;
                    const size_t idx = obase + (size_t)(f0 + feat) * T_DIM + t;
                    out[idx] = x[idx] + O1t[g][ft][r] * i1[g] - O2t[g][ft][r] * i2[g];
                }
            }
        }
    }
}

extern "C" void kernel_launch(void* const* d_in, const int* in_sizes, int n_in,
                              void* d_out, int out_size, void* d_ws, size_t ws_size,
                              hipStream_t stream)
{
    const float* x  = (const float*)d_in[0];
    const float* Wq = (const float*)d_in[1];
    const float* bq = (const float*)d_in[2];
    const float* Wk = (const float*)d_in[3];
    const float* bk = (const float*)d_in[4];
    const float* Wv = (const float*)d_in[5];
    const float* bv = (const float*)d_in[6];
    const float* s2 = (const float*)d_in[7];
    float* out = (float*)d_out;

    const size_t per = (size_t)B_DIM * T_DIM * F_DIM;
    const size_t wsz = (size_t)F_DIM * F_DIM;
    unsigned short* xt  = (unsigned short*)d_ws;
    unsigned short* Wqb = xt + per;
    unsigned short* Wkb = Wqb + wsz;
    unsigned short* Wvb = Wkb + wsz;
    unsigned short* Qb  = Wvb + wsz;
    unsigned short* Kb  = Qb + per;
    unsigned short* Vtb = Kb + per;

    hipLaunchKernelGGL(prep_kernel, dim3(32, 8, 5), dim3(256), 0, stream,
                       x, Wq, Wk, Wv, xt, Wqb, Wkb, Wvb);

    hipLaunchKernelGGL(proj_kernel, dim3(16, 8, 12), dim3(256), 0, stream,
                       xt, Wqb, Wkb, Wvb, bq, bk, bv, Qb, Kb, Vtb);

    hipLaunchKernelGGL(attn_kernel, dim3(16, 4, 4), dim3(512), 0, stream,
                       Qb, Kb, Vtb, x, s2, out);
}

// Round 8
// 92.489 us; speedup vs baseline: 2.0105x; 1.0050x over previous
//
#include <hip/hip_runtime.h>
#include <math.h>

#define B_DIM 4
#define F_DIM 512
#define T_DIM 2048
#define H_DIM 4
#define HF    128

typedef __attribute__((ext_vector_type(8))) short short8;
typedef __attribute__((ext_vector_type(4))) float floatx4;

// round-half-up bf16 (2 inst)
__device__ __forceinline__ unsigned short f2bf(float f) {
    return (unsigned short)((__float_as_uint(f) + 0x8000u) >> 16);
}

// two floats -> packed bf16 pair: 2 adds + 1 v_perm_b32
__device__ __forceinline__ unsigned pkbf2(float a, float b) {
    const unsigned ua = __float_as_uint(a) + 0x8000u;
    const unsigned ub = __float_as_uint(b) + 0x8000u;
    return __builtin_amdgcn_perm(ub, ua, 0x07060302u);  // [ua.hi16 | ub.hi16]
}

__device__ __forceinline__ short8 pack8(const float* v) {
    union { unsigned u[4]; short8 s; } r;
    #pragma unroll
    for (int j = 0; j < 4; ++j) r.u[j] = pkbf2(v[2*j], v[2*j+1]);
    return r.s;
}

// direct-to-LDS 16B load: per-lane global src, wave-uniform LDS base + lane*16
__device__ __forceinline__ void gload16(const unsigned short* g, unsigned short* l) {
    __builtin_amdgcn_global_load_lds(
        (const __attribute__((address_space(1))) void*)g,
        (__attribute__((address_space(3))) void*)l, 16, 0, 0);
}

// ---------------- Kernel 0: prep ----------------
__global__ __launch_bounds__(256)
void prep_kernel(const float* __restrict__ x,
                 const float* __restrict__ Wq, const float* __restrict__ Wk,
                 const float* __restrict__ Wv,
                 unsigned short* __restrict__ xt,
                 unsigned short* __restrict__ Wqb, unsigned short* __restrict__ Wkb,
                 unsigned short* __restrict__ Wvb)
{
    const int tid = threadIdx.x;
    if (blockIdx.z < B_DIM) {
        const int b  = blockIdx.z;
        const int t0 = blockIdx.x * 64;
        const int f0 = blockIdx.y * 64;
        __shared__ float Ls[64][67];
        const float* __restrict__ xb = x + (size_t)b * F_DIM * T_DIM;
        #pragma unroll
        for (int it = 0; it < 4; ++it) {
            const int fr = (tid >> 4) + 16 * it;
            const int tc = (tid & 15) << 2;
            const float4 v = *(const float4*)(xb + (size_t)(f0 + fr) * T_DIM + t0 + tc);
            Ls[fr][tc+0] = v.x; Ls[fr][tc+1] = v.y; Ls[fr][tc+2] = v.z; Ls[fr][tc+3] = v.w;
        }
        __syncthreads();
        const int f8 = tid & 7;
        const int tb = tid >> 3;
        #pragma unroll
        for (int it2 = 0; it2 < 2; ++it2) {
            const int t = tb + 32 * it2;
            float v[8];
            #pragma unroll
            for (int j = 0; j < 8; ++j) v[j] = Ls[8*f8 + j][t];
            *(short8*)(xt + ((size_t)b * T_DIM + t0 + t) * F_DIM + f0 + 8*f8) = pack8(v);
        }
    } else {
        const int blockId = blockIdx.y * 32 + blockIdx.x;
        const int g0 = blockId * 256 + tid;
        const int perW = F_DIM * F_DIM / 8;
        for (int chunk = g0; chunk < 3 * perW; chunk += 65536) {
            const int wsel = chunk / perW;
            const int rem  = chunk - wsel * perW;
            const float* __restrict__ Ws = (wsel == 0) ? Wq : (wsel == 1) ? Wk : Wv;
            unsigned short* __restrict__ Wd = (wsel == 0) ? Wqb : (wsel == 1) ? Wkb : Wvb;
            float v[8];
            *(float4*)&v[0] = *(const float4*)(Ws + (size_t)rem * 8);
            *(float4*)&v[4] = *(const float4*)(Ws + (size_t)rem * 8 + 4);
            *(short8*)(Wd + (size_t)rem * 8) = pack8(v);
        }
    }
}

// ---------------- Kernel 1: merged QKV projection, 128x128 tiles ----------
// R14: tile widened 128x64 -> 128x128 (acc[2][8]) on the R13-validated
// gload_lds + XOR-granule-swizzle staging. Each a[mi] ds_read now feeds 8
// MFMAs (was 4); staging bytes/output 24->16 B; barriers/output halved;
// RoPE sincos shared across the two 64-col groups (u depends on t,pr only).
// A and B tiles are both 128 rows -> one shared per-lane offset array.
// LDS 64 KB -> 2 blocks/CU.
__global__ __launch_bounds__(256, 2)
void proj_kernel(const unsigned short* __restrict__ xt,
                 const unsigned short* __restrict__ Wqb,
                 const unsigned short* __restrict__ Wkb,
                 const unsigned short* __restrict__ Wvb,
                 const float* __restrict__ bq, const float* __restrict__ bk,
                 const float* __restrict__ bv,
                 unsigned short* __restrict__ Qb, unsigned short* __restrict__ Kb,
                 unsigned short* __restrict__ Vtb)
{
    __shared__ unsigned short As[128][128];   // 32 KB, linear rows, XOR-swizzled granules
    __shared__ unsigned short Bs[128][128];   // 32 KB

    const int tid  = threadIdx.x;
    const int w    = tid >> 6;
    const int lane = tid & 63;
    const int ln15 = lane & 15;
    const int quad = lane >> 4;

    // XCD-chunked swizzle of the 64-block (x,y) plane (z untouched).
    const int flat = blockIdx.x + 8 * blockIdx.y;        // 0..63
    const int fswz = (flat & 7) * 8 + (flat >> 3);       // bijective, 64%8==0
    const bool is_v = (blockIdx.z >= 8);

    int t0, fo0, b;
    const unsigned short *Asrc, *Bsrc;
    if (!is_v) {
        t0  = (fswz & 15) * 128;                         // 16 M-tiles (t)
        fo0 = (fswz >> 4) * 128;                         // 4  N-tiles (fo)
        b   = blockIdx.z >> 1;
        Asrc = xt + (size_t)b * T_DIM * F_DIM + (size_t)t0 * F_DIM;
        Bsrc = ((blockIdx.z & 1) ? Wkb : Wqb) + (size_t)fo0 * F_DIM;
    } else {
        fo0 = (fswz >> 4) * 128;                         // 4  M-tiles (fo)
        t0  = (fswz & 15) * 128;                         // 16 N-tiles (t)
        b   = blockIdx.z - 8;
        Asrc = Wvb + (size_t)fo0 * F_DIM;
        Bsrc = xt + (size_t)b * T_DIM * F_DIM + (size_t)t0 * F_DIM;
    }

    // Per-lane inverse-swizzled source offsets (granule = 8 shorts = 16 B).
    // Dest (rd, cd) <- src granule g = cd ^ (rd&15). A and B share this.
    int off[8];
    #pragma unroll
    for (int it = 0; it < 8; ++it) {
        const int rd = w * 32 + it * 4 + (lane >> 4);
        const int g  = (lane & 15) ^ (rd & 15);
        off[it] = rd * F_DIM + g * 8;
    }

    floatx4 acc[2][8];
    #pragma unroll
    for (int mi = 0; mi < 2; ++mi)
        #pragma unroll
        for (int nt = 0; nt < 8; ++nt) acc[mi][nt] = (floatx4){0.f,0.f,0.f,0.f};

    for (int f0 = 0; f0 < F_DIM; f0 += 128) {
        __syncthreads();                     // previous compute's reads done
        #pragma unroll
        for (int it = 0; it < 8; ++it)       // A: wave w stages rows [w*32, w*32+32)
            gload16(Asrc + off[it] + f0, &As[w * 32 + it * 4][0]);
        #pragma unroll
        for (int it = 0; it < 8; ++it)       // B: same row range
            gload16(Bsrc + off[it] + f0, &Bs[w * 32 + it * 4][0]);
        asm volatile("s_waitcnt vmcnt(0)" ::: "memory");
        __syncthreads();                     // tiles visible
        #pragma unroll
        for (int ks = 0; ks < 4; ++ks) {
            short8 a[2], bb[8];
            #pragma unroll
            for (int mi = 0; mi < 2; ++mi) {
                const int r = w * 32 + 16 * mi + ln15;
                a[mi] = *(const short8*)&As[r][(((ks * 4 + quad) ^ (r & 15))) * 8];
            }
            #pragma unroll
            for (int nt = 0; nt < 8; ++nt) {
                const int r = 16 * nt + ln15;
                bb[nt] = *(const short8*)&Bs[r][(((ks * 4 + quad) ^ (r & 15))) * 8];
            }
            #pragma unroll
            for (int mi = 0; mi < 2; ++mi)
                #pragma unroll
                for (int nt = 0; nt < 8; ++nt)
                    acc[mi][nt] = __builtin_amdgcn_mfma_f32_16x16x32_bf16(
                        a[mi], bb[nt], acc[mi][nt], 0, 0, 0);
        }
    }

    if (!is_v) {
        const int which = blockIdx.z & 1;
        const float* bias = which ? bk : bq;
        unsigned short* __restrict__ Out =
            (which ? Kb : Qb) + (size_t)b * T_DIM * F_DIM;
        // Q carries 1/sqrt(F/2) * log2(e) so attn can use exp2 (v_exp_f32 native)
        const float oscale = which ? 1.0f : 0.0625f * 1.4426950408889634f;
        float bn[8];
        #pragma unroll
        for (int nt = 0; nt < 8; ++nt) bn[nt] = bias[fo0 + 16*nt + ln15];
        const float pw[2] = {
            __uint_as_float((unsigned)(123 - ln15) << 23),   // 2^-(ln15+4)
            __uint_as_float((unsigned)(107 - ln15) << 23)    // 2^-(ln15+20)
        };
        #pragma unroll
        for (int mi = 0; mi < 2; ++mi) {
            #pragma unroll
            for (int r = 0; r < 4; ++r) {
                const int t = t0 + w*32 + 16*mi + quad*4 + r;
                unsigned short* rowp = Out + (size_t)t * F_DIM + fo0;
                #pragma unroll
                for (int pr = 0; pr < 2; ++pr) {
                    const float u = (float)t * pw[pr];
                    float sn, cs;
                    __sincosf(u, &sn, &cs);      // shared by both 64-col groups
                    #pragma unroll
                    for (int blk = 0; blk < 2; ++blk) {
                        const int wi = blk*64 + 16*pr + ln15;
                        const float re = acc[mi][blk*4 + pr    ][r] + bn[blk*4 + pr];
                        const float im = acc[mi][blk*4 + pr + 2][r] + bn[blk*4 + pr + 2];
                        rowp[wi]      = f2bf((re * sn - im * cs) * oscale);
                        rowp[wi + 32] = f2bf((re * cs + im * sn) * oscale);
                    }
                }
            }
        }
    } else {
        #pragma unroll
        for (int mi = 0; mi < 2; ++mi) {
            #pragma unroll
            for (int r = 0; r < 4; ++r) {
                const int fo = fo0 + w*32 + 16*mi + quad*4 + r;
                const float bvv = bv[fo];
                unsigned short* rowp = Vtb + ((size_t)b * F_DIM + fo) * T_DIM + t0;
                #pragma unroll
                for (int nt = 0; nt < 8; ++nt)
                    rowp[16*nt + ln15] = f2bf(acc[mi][nt][r] + bvv);
            }
        }
    }
}

// ---------------- Kernel 2: S^T MFMA flash attention, nq=32/wave -----------
// R12-R14: verbatim Round-1 (R7) attn kernel — thrice measured ~70 us, no
// spill. R8-R11 showed ANY mutation of this loop body (reorders, setprio,
// even FP reassociation) tips the allocator past the 256-reg cliff into
// scratch spill. This schedule is the proven fit; do not touch.
__global__ __launch_bounds__(512, 2)
void attn_kernel(const unsigned short* __restrict__ Qb,
                 const unsigned short* __restrict__ Kb,
                 const unsigned short* __restrict__ Vtb,
                 const float* __restrict__ x,
                 const float* __restrict__ s2g,
                 float* __restrict__ out)
{
    __shared__ unsigned short smem[2][2][16384];   // [half][buf][K 8192 | V 8192] = 128 KB

    const int tid  = threadIdx.x;
    const int w8   = tid >> 6;
    const int half = w8 >> 2;
    const int qg   = w8 & 3;          // q-group index == staging slice index
    const int lane = tid & 63;
    const int ln15 = lane & 15;
    const int quad = lane >> 4;

    // XCD-chunked swizzle: 256 blocks, chunk 32 -> each XCD owns 2 (b,h) pairs
    const int flat = blockIdx.x + 16 * (blockIdx.y + 4 * blockIdx.z);
    const int swz  = (flat & 7) * 32 + (flat >> 3);
    const int q0 = (swz & 15) * 128;
    const int h  = (swz >> 4) & 3;
    const int b  = swz >> 6;

    const int kbase = half << 10;   // 0 or 1024

    const unsigned short* __restrict__ Qg =
        Qb + ((size_t)b * T_DIM + q0 + qg * 32) * F_DIM + h * HF;
    const unsigned short* __restrict__ Kg =
        Kb + (size_t)b * T_DIM * F_DIM + h * HF;
    const unsigned short* __restrict__ Vg =
        Vtb + ((size_t)b * F_DIM + h * HF) * T_DIM;

    // Per-lane inverse-swizzled global source offsets so that linear
    // global_load_lds (uniform base + lane*16) reproduces the swizzled layout:
    //   K LDS: dest row rd holds source row r=inv(rd), col granule cd = c^(rd&15)
    //     forward perm: rp = (r&32)|((r&4)<<2)|((r&24)>>1)|(r&3)
    //     inverse:      r  = (rd&32)|((rd&12)<<1)|((rd&16)>>2)|(rd&3)
    //   V LDS: dest row rd = feat, col granule cd = c^(rd&7)
    int koff[4], voff[4];
    #pragma unroll
    for (int it = 0; it < 4; ++it) {
        const int m = qg * 4 + it;
        {
            const int rd = 4 * m + (lane >> 4);
            const int r  = (rd & 32) | ((rd & 12) << 1) | ((rd & 16) >> 2) | (rd & 3);
            const int c  = (lane & 15) ^ (rd & 15);
            koff[it] = r * F_DIM + c * 8;
        }
        {
            const int rd = 8 * m + (lane >> 3);
            const int c  = (lane & 7) ^ (rd & 7);
            voff[it] = rd * T_DIM + c * 8;
        }
    }

    auto stage = [&](int buf, int k) {
        unsigned short* Kd = &smem[half][buf][0]    + qg * 2048;
        unsigned short* Vd = &smem[half][buf][8192] + qg * 2048;
        const unsigned short* Kp = Kg + (size_t)(kbase + k) * F_DIM;
        const unsigned short* Vp = Vg + (kbase + k);
        #pragma unroll
        for (int it = 0; it < 4; ++it) {
            gload16(Kp + koff[it], Kd + it * 512);
            gload16(Vp + voff[it], Vd + it * 512);
        }
    };

    // Q B-frags (resident): B[k=feat][n=q=ln15], two 16-q groups
    short8 qa[2][4];
    #pragma unroll
    for (int g = 0; g < 2; ++g)
        #pragma unroll
        for (int c = 0; c < 4; ++c)
            qa[g][c] = *(const short8*)(Qg + (size_t)(g * 16 + ln15) * F_DIM + quad * 8 + 32 * c);

    floatx4 O1t[2][8], O2t[2][8];
    #pragma unroll
    for (int g = 0; g < 2; ++g)
        #pragma unroll
        for (int ft = 0; ft < 8; ++ft) {
            O1t[g][ft] = (floatx4){0.f, 0.f, 0.f, 0.f};
            O2t[g][ft] = (floatx4){0.f, 0.f, 0.f, 0.f};
        }
    float l1[2] = {0.f, 0.f}, l2[2] = {0.f, 0.f};

    stage(0, 0);   // prologue: tile 0 -> buf 0

    for (int k0 = 0; k0 < 1024; k0 += 64) {
        asm volatile("s_waitcnt vmcnt(0)" ::: "memory");  // own tile-k0 DMA done
        __syncthreads();                                   // everyone's tile in LDS
        const int buf = (k0 >> 6) & 1;
        if (k0 + 64 < 1024) stage(buf ^ 1, k0 + 64);       // in flight across compute

        const unsigned short* Ks = &smem[half][buf][0];
        const unsigned short* Vs = &smem[half][buf][8192];

        // ---- scores S^T[k][q] + no-max softmax numerators p = 2^S ----
        short8 p1f[2][2], p2f[2][2];
        #pragma unroll
        for (int tp = 0; tp < 2; ++tp) {
            float e1[2][8], e2[2][8];
            #pragma unroll
            for (int tt = 0; tt < 2; ++tt) {
                const int t = tp * 2 + tt;
                const unsigned short* krow = &Ks[(16 * t + ln15) * 128];
                const short8 k0f = *(const short8*)(krow + ((quad     ) ^ ln15) * 8);
                const short8 k1f = *(const short8*)(krow + ((quad +  4) ^ ln15) * 8);
                const short8 k2f = *(const short8*)(krow + ((quad +  8) ^ ln15) * 8);
                const short8 k3f = *(const short8*)(krow + ((quad + 12) ^ ln15) * 8);
                #pragma unroll
                for (int g = 0; g < 2; ++g) {
                    floatx4 z = (floatx4){0.f, 0.f, 0.f, 0.f};
                    floatx4 s = __builtin_amdgcn_mfma_f32_16x16x32_bf16(k0f, qa[g][0], z, 0, 0, 0);
                    s         = __builtin_amdgcn_mfma_f32_16x16x32_bf16(k1f, qa[g][1], s, 0, 0, 0);
                    floatx4 u = __builtin_amdgcn_mfma_f32_16x16x32_bf16(k2f, qa[g][2], z, 0, 0, 0);
                    u         = __builtin_amdgcn_mfma_f32_16x16x32_bf16(k3f, qa[g][3], u, 0, 0, 0);
                    #pragma unroll
                    for (int r = 0; r < 4; ++r) {
                        e1[g][tt*4 + r] = __builtin_amdgcn_exp2f(s[r]);
                        e2[g][tt*4 + r] = __builtin_amdgcn_exp2f(u[r]);
                    }
                }
            }
            #pragma unroll
            for (int g = 0; g < 2; ++g) {
                #pragma unroll
                for (int j = 0; j < 8; ++j) { l1[g] += e1[g][j]; l2[g] += e2[g][j]; }
                p1f[g][tp] = pack8(&e1[g][0]);
                p2f[g][tp] = pack8(&e2[g][0]);
            }
        }

        // ---- PV: O^T += V^T . P^T (each va read feeds 4 MFMAs) ----
        #pragma unroll
        for (int p = 0; p < 2; ++p) {
            #pragma unroll
            for (int ft = 0; ft < 8; ++ft) {
                const short8 va = *(const short8*)
                    (&Vs[(16*ft + ln15) * 64 + (((4*p + quad) ^ (ln15 & 7))) * 8]);
                O1t[0][ft] = __builtin_amdgcn_mfma_f32_16x16x32_bf16(va, p1f[0][p], O1t[0][ft], 0, 0, 0);
                O1t[1][ft] = __builtin_amdgcn_mfma_f32_16x16x32_bf16(va, p1f[1][p], O1t[1][ft], 0, 0, 0);
                O2t[0][ft] = __builtin_amdgcn_mfma_f32_16x16x32_bf16(va, p2f[0][p], O2t[0][ft], 0, 0, 0);
                O2t[1][ft] = __builtin_amdgcn_mfma_f32_16x16x32_bf16(va, p2f[1][p], O2t[1][ft], 0, 0, 0);
            }
        }
    }

    // ---- reductions: intra-wave l across quads, then cross-half via LDS ----
    #pragma unroll
    for (int g = 0; g < 2; ++g) {
        l1[g] += __shfl_xor(l1[g], 16); l1[g] += __shfl_xor(l1[g], 32);
        l2[g] += __shfl_xor(l2[g], 16); l2[g] += __shfl_xor(l2[g], 32);
    }

    float* comb = (float*)&smem[0][0][0];
    __syncthreads();   // all compute done, smem reusable
    if (half == 1) {
        if (quad == 0) {
            #pragma unroll
            for (int g = 0; g < 2; ++g) {
                comb[      qg*32 + g*16 + ln15] = l1[g];
                comb[128 + qg*32 + g*16 + ln15] = l2[g];
            }
        }
        #pragma unroll
        for (int g = 0; g < 2; ++g)
            #pragma unroll
            for (int ft = 0; ft < 8; ++ft)
                #pragma unroll
                for (int r = 0; r < 4; ++r)
                    comb[512 + (((g*8 + ft)*4 + r) * 256) + qg*64 + lane] = O1t[g][ft][r];
    }
    __syncthreads();
    if (half == 0) {
        #pragma unroll
        for (int g = 0; g < 2; ++g) {
            l1[g] += comb[      qg*32 + g*16 + ln15];
            l2[g] += comb[128 + qg*32 + g*16 + ln15];
        }
        #pragma unroll
        for (int g = 0; g < 2; ++g)
            #pragma unroll
            for (int ft = 0; ft < 8; ++ft)
                #pragma unroll
                for (int r = 0; r < 4; ++r)
                    O1t[g][ft][r] += comb[512 + (((g*8 + ft)*4 + r) * 256) + qg*64 + lane];
    }
    __syncthreads();
    if (half == 1) {
        #pragma unroll
        for (int g = 0; g < 2; ++g)
            #pragma unroll
            for (int ft = 0; ft < 8; ++ft)
                #pragma unroll
                for (int r = 0; r < 4; ++r)
                    comb[512 + (((g*8 + ft)*4 + r) * 256) + qg*64 + lane] = O2t[g][ft][r];
    }
    __syncthreads();
    if (half == 0) {
        #pragma unroll
        for (int g = 0; g < 2; ++g)
            #pragma unroll
            for (int ft = 0; ft < 8; ++ft)
                #pragma unroll
                for (int r = 0; r < 4; ++r)
                    O2t[g][ft][r] += comb[512 + (((g*8 + ft)*4 + r) * 256) + qg*64 + lane];

        // ---- epilogue: out = x + O1/l1 - s2*O2/l2, layout [B][F][T] ----
        const float s2h = s2g[h];
        float i1[2], i2[2];
        #pragma unroll
        for (int g = 0; g < 2; ++g) { i1[g] = 1.f / l1[g]; i2[g] = s2h / l2[g]; }
        const size_t obase = (size_t)b * F_DIM * T_DIM;
        const int f0 = h * HF;
        #pragma unroll
        for (int g = 0; g < 2; ++g) {
            const int t = q0 + qg*32 + g*16 + ln15;
            #pragma unroll
            for (int ft = 0; ft < 8; ++ft) {
                #pragma unroll
                for (int r = 0; r < 4; ++r) {
                    const int feat = 16*ft + 4*quad + r;
                    const size_t idx = obase + (size_t)(f0 + feat) * T_DIM + t;
                    out[idx] = x[idx] + O1t[g][ft][r] * i1[g] - O2t[g][ft][r] * i2[g];
                }
            }
        }
    }
}

extern "C" void kernel_launch(void* const* d_in, const int* in_sizes, int n_in,
                              void* d_out, int out_size, void* d_ws, size_t ws_size,
                              hipStream_t stream)
{
    const float* x  = (const float*)d_in[0];
    const float* Wq = (const float*)d_in[1];
    const float* bq = (const float*)d_in[2];
    const float* Wk = (const float*)d_in[3];
    const float* bk = (const float*)d_in[4];
    const float* Wv = (const float*)d_in[5];
    const float* bv = (const float*)d_in[6];
    const float* s2 = (const float*)d_in[7];
    float* out = (float*)d_out;

    const size_t per = (size_t)B_DIM * T_DIM * F_DIM;
    const size_t wsz = (size_t)F_DIM * F_DIM;
    unsigned short* xt  = (unsigned short*)d_ws;
    unsigned short* Wqb = xt + per;
    unsigned short* Wkb = Wqb + wsz;
    unsigned short* Wvb = Wkb + wsz;
    unsigned short* Qb  = Wvb + wsz;
    unsigned short* Kb  = Qb + per;
    unsigned short* Vtb = Kb + per;

    hipLaunchKernelGGL(prep_kernel, dim3(32, 8, 5), dim3(256), 0, stream,
                       x, Wq, Wk, Wv, xt, Wqb, Wkb, Wvb);

    hipLaunchKernelGGL(proj_kernel, dim3(8, 8, 12), dim3(256), 0, stream,
                       xt, Wqb, Wkb, Wvb, bq, bk, bv, Qb, Kb, Vtb);

    hipLaunchKernelGGL(attn_kernel, dim3(16, 4, 4), dim3(512), 0, stream,
                       Qb, Kb, Vtb, x, s2, out);
}